// Round 12
// baseline (364.185 us; speedup 1.0000x reference)
//
#include <hip/hip_runtime.h>

#define N_NODES   50000
#define N_EDGES   1600000
#define DDIM      64
#define N_GRAPHS  512
#define N_CLASSES 53
#define ITERS     3
#define NB        782            // ceil(N_NODES/64) buckets of 64 dst nodes
#define PPITCH    800            // partial row pitch (>= NB)
#define NXCD      8
#define XBUCK     98             // buckets per XCD range (98*8 = 784 >= NB)
#define NCHUNK    64             // edge chunks; grid = NXCD * NCHUNK = 512
#define ECHUNK    ((N_EDGES + NCHUNK - 1) / NCHUNK)

typedef __bf16 bf16x8 __attribute__((ext_vector_type(8)));
typedef __bf16 bf16x4 __attribute__((ext_vector_type(4)));
typedef float  f32x4  __attribute__((ext_vector_type(4)));

__device__ __forceinline__ float blo16(unsigned w) { return __uint_as_float(w << 16); }
__device__ __forceinline__ float bhi16(unsigned w) { return __uint_as_float(w & 0xffff0000u); }

// hb[node][d] = bf16(emb[pkt[node]][d]) — bf16 node features (halves gather traffic)
__global__ void embed_kernel(const int* __restrict__ pkt, const float4* __restrict__ emb,
                             bf16x4* __restrict__ hb4) {
  int idx = blockIdx.x * 256 + threadIdx.x;           // over N_NODES*16 float4s
  if (idx >= N_NODES * 16) return;
  int node = idx >> 4;
  float4 v = emb[(size_t)pkt[node] * 16 + (idx & 15)];
  bf16x4 o;
  o[0] = (__bf16)v.x; o[1] = (__bf16)v.y; o[2] = (__bf16)v.z; o[3] = (__bf16)v.w;
  hb4[idx] = o;
}

// edge-count per 64-node dst bucket, LDS-staged
__global__ void bucket_hist_kernel(const int* __restrict__ dst, int* __restrict__ bhist) {
  __shared__ int lh[NB];
  for (int i = threadIdx.x; i < NB; i += 256) lh[i] = 0;
  __syncthreads();
  int stride = gridDim.x * 256;
  for (int e = blockIdx.x * 256 + threadIdx.x; e < N_EDGES; e += stride)
    atomicAdd(&lh[dst[e] >> 6], 1);
  __syncthreads();
  for (int i = threadIdx.x; i < NB; i += 256)
    if (lh[i]) atomicAdd(&bhist[i], lh[i]);
}

__global__ void hist_kernel(const int* __restrict__ idx, int* __restrict__ counts, int n) {
  int i = blockIdx.x * 256 + threadIdx.x;
  if (i < n) atomicAdd(&counts[idx[i]], 1);
}

// single-block exclusive scan body; offs[n] = total; optional cursor copy
__device__ void scan_body(const int* __restrict__ counts, int* __restrict__ offs,
                          int* __restrict__ cursor, int n) {
  __shared__ int wsum[16];
  __shared__ int carry;
  int tid = threadIdx.x;               // 1024 threads
  if (tid == 0) carry = 0;
  __syncthreads();
  for (int base = 0; base < n; base += 1024) {
    int i = base + tid;
    int v = (i < n) ? counts[i] : 0;
    int x = v;
    #pragma unroll
    for (int off = 1; off < 64; off <<= 1) {
      int y = __shfl_up(x, off);
      if ((tid & 63) >= off) x += y;
    }
    int w = tid >> 6;
    if ((tid & 63) == 63) wsum[w] = x;
    __syncthreads();
    int woff = 0;
    for (int k = 0; k < w; ++k) woff += wsum[k];
    int incl = x + woff + carry;
    if (i < n) {
      offs[i] = incl - v;
      if (cursor) cursor[i] = incl - v;
    }
    __syncthreads();
    if (tid == 1023) carry = incl;
    __syncthreads();
  }
  if (tid == 0) offs[n] = carry;
}

// both prologue scans in one launch (block 0: buckets, block 1: graphs)
__global__ void scans_kernel(const int* __restrict__ bhist, int* __restrict__ boffs,
                             int* __restrict__ bcursor, const int* __restrict__ gcnt,
                             int* __restrict__ goff) {
  if (blockIdx.x == 0) scan_body(bhist, boffs, bcursor, NB);
  else                 scan_body(gcnt, goff, nullptr, N_GRAPHS);
}

// bucket-partition, XCD-sliced: block i handles bucket range (i&7) x chunk (i>>3).
// All writes to a bucket's ebuf region come from blocks with the same (i&7)
// residue -> same XCD under round-robin dispatch -> single-XCD dirty lines,
// killing the 6-7x cross-XCD writeback amplification measured in R10/R11.
__global__ __launch_bounds__(256) void partition_kernel(
    const int* __restrict__ src, const int* __restrict__ dst,
    int* __restrict__ bcursor, unsigned* __restrict__ ebuf) {
  const int xr = blockIdx.x & (NXCD - 1);
  const int ck = blockIdx.x >> 3;
  const int b0 = xr * XBUCK;
  const int b1 = min(b0 + XBUCK, NB);
  __shared__ int lh[XBUCK];
  __shared__ int lbase[XBUCK];
  for (int i = threadIdx.x; i < XBUCK; i += 256) lh[i] = 0;
  __syncthreads();
  const int e0 = ck * ECHUNK;
  const int e1 = min(e0 + ECHUNK, N_EDGES);
  for (int e = e0 + (int)threadIdx.x; e < e1; e += 256) {
    int b = dst[e] >> 6;
    if (b >= b0 && b < b1) atomicAdd(&lh[b - b0], 1);
  }
  __syncthreads();
  for (int i = threadIdx.x; i < XBUCK; i += 256) {
    int c = lh[i];
    lbase[i] = c ? atomicAdd(&bcursor[b0 + i], c) : 0;
    lh[i] = 0;                         // reuse as running cursor
  }
  __syncthreads();
  for (int e = e0 + (int)threadIdx.x; e < e1; e += 256) {
    int d = dst[e];
    int b = d >> 6;
    if (b >= b0 && b < b1) {
      int pos = lbase[b - b0] + atomicAdd(&lh[b - b0], 1);
      ebuf[pos] = (unsigned)src[e] | ((unsigned)(d & 63) << 16);
    }
  }
}

// block per bucket: per-node offsets (in-block 64-scan) + CSR scatter locally
__global__ __launch_bounds__(256) void local_scatter_kernel(
    const unsigned* __restrict__ ebuf, const int* __restrict__ boffs,
    int* __restrict__ offs, int* __restrict__ csr) {
  __shared__ int cnt[64];
  __shared__ int base[64];
  const int b = blockIdx.x;
  const int tid = threadIdx.x;
  if (tid < 64) cnt[tid] = 0;
  __syncthreads();
  const int ebeg = boffs[b], eend = boffs[b + 1];
  for (int e = ebeg + tid; e < eend; e += 256)
    atomicAdd(&cnt[(ebuf[e] >> 16) & 63u], 1);
  __syncthreads();
  if (tid < 64) {                      // wave 0: exclusive scan of 64 counts
    int v = cnt[tid];
    int x = v;
    #pragma unroll
    for (int off = 1; off < 64; off <<= 1) {
      int y = __shfl_up(x, off);
      if (tid >= off) x += y;
    }
    int excl = ebeg + x - v;
    base[tid] = excl;
    int node = b * 64 + tid;
    if (node < N_NODES) offs[node] = excl;
    cnt[tid] = 0;                      // reuse as running cursor
  }
  __syncthreads();
  for (int e = ebeg + tid; e < eend; e += 256) {
    unsigned p = ebuf[e];
    int j = (p >> 16) & 63u;
    int pos = base[j] + atomicAdd(&cnt[j], 1);
    csr[pos] = (int)(p & 0xFFFFu);
  }
  if (b == NB - 1 && tid == 0) offs[N_NODES] = N_EDGES;
}

// x[v] = (1+eps)*hb[v] + sum_u hb[u].
// 8-lane GROUP per node: the 8 lanes fetch the source row as 8x uint4 (128B,
// dwordx4) -> 8 edges per wave-load-instruction, no cross-lane reduction.
__global__ __launch_bounds__(256) void aggregate_kernel(
    const __bf16* __restrict__ hb, const int* __restrict__ offs,
    const int* __restrict__ csr, const float* __restrict__ epsp,
    float* __restrict__ x) {
  const int lane = threadIdx.x & 63;
  const int wave = threadIdx.x >> 6;
  const int fl = lane & 7;             // feature-block index
  const int eg = lane >> 3;            // node sub-group 0..7
  const int node = blockIdx.x * 32 + wave * 8 + eg;
  const bool nvalid = node < N_NODES;
  const uint4* __restrict__ hrow4 = (const uint4*)hb;   // [node][8] uint4

  int beg = 0, end = 0;
  if (nvalid) { beg = offs[node]; end = offs[node + 1]; }
  const int deg = end - beg;
  int maxdeg = deg;                    // max over the wave's 8 groups
  maxdeg = max(maxdeg, __shfl_xor(maxdeg, 8));
  maxdeg = max(maxdeg, __shfl_xor(maxdeg, 16));
  maxdeg = max(maxdeg, __shfl_xor(maxdeg, 32));

  float a0 = 0.f, a1 = 0.f, a2 = 0.f, a3 = 0.f, a4 = 0.f, a5 = 0.f, a6 = 0.f, a7 = 0.f;
  if (nvalid) {                        // self term (1+eps)*h[v]
    uint4 w = hrow4[(size_t)node * 8 + fl];
    float ep = 1.0f + epsp[0];
    a0 = ep * blo16(w.x); a1 = ep * bhi16(w.x);
    a2 = ep * blo16(w.y); a3 = ep * bhi16(w.y);
    a4 = ep * blo16(w.z); a5 = ep * bhi16(w.z);
    a6 = ep * blo16(w.w); a7 = ep * bhi16(w.w);
  }

  #pragma unroll 4
  for (int it = 0; it < maxdeg; ++it) {
    bool act = it < deg;
    int ci = beg + it;
    ci = (ci < N_EDGES) ? ci : 0;      // clamp: unconditional, uniform loads
    int u = csr[ci];
    uint4 w = hrow4[(size_t)u * 8 + fl];
    unsigned m = act ? 0xffffffffu : 0u;
    w.x &= m; w.y &= m; w.z &= m; w.w &= m;
    a0 += blo16(w.x); a1 += bhi16(w.x);
    a2 += blo16(w.y); a3 += bhi16(w.y);
    a4 += blo16(w.z); a5 += bhi16(w.z);
    a6 += blo16(w.w); a7 += bhi16(w.w);
  }

  if (nvalid) {
    float* xp = x + (size_t)node * DDIM + fl * 8;
    float4 o0 = {a0, a1, a2, a3};
    float4 o1 = {a4, a5, a6, a7};
    *(float4*)xp = o0;
    *(float4*)(xp + 4) = o1;
  }
}

// pack W1,W2,W3 into MFMA B-fragment order, SPLIT bf16: hi=bf16(w), lo=bf16(w-hi).
__global__ void pack_weights_kernel(const float* __restrict__ W1, const float* __restrict__ W2,
                                    const float* __restrict__ W3, bf16x8* __restrict__ wbuf) {
  int i = blockIdx.x * 256 + threadIdx.x;
  if (i >= 24 * 64) return;
  int lane = i & 63;
  int frag = i >> 6;
  int t = frag & 3;
  int kc = (frag >> 2) & 1;
  int L = frag >> 3;
  const float* W = (L == 0) ? W1 : ((L == 1) ? W2 : W3);
  int l15 = lane & 15, lg = lane >> 4;
  bf16x8 fh, fl;
  #pragma unroll
  for (int e = 0; e < 8; ++e) {
    int k = kc * 32 + lg * 8 + e;
    float w = W[k * 64 + t * 16 + l15];
    __bf16 hi = (__bf16)w;
    fh[e] = hi;
    fl[e] = (__bf16)(w - (float)hi);
  }
  wbuf[i] = fh;
  wbuf[24 * 64 + i] = fl;
}

__device__ __forceinline__ void split8(const f32x4& v0, const f32x4& v1,
                                       bf16x8& hi, bf16x8& lo) {
  #pragma unroll
  for (int e = 0; e < 4; ++e) {
    __bf16 h0 = (__bf16)v0[e];
    __bf16 h1 = (__bf16)v1[e];
    hi[e] = h0;     lo[e] = (__bf16)(v0[e] - (float)h0);
    hi[4 + e] = h1; lo[4 + e] = (__bf16)(v1[e] - (float)h1);
  }
}

#define MFMA(A, B, C) __builtin_amdgcn_mfma_f32_16x16x32_bf16((A), (B), (C), 0, 0, 0)

// one output col-tile T of layer L: 3-term split-bf16 product, all names literal.
#define DOT(L, T, BIASV, ACC)                                        \
  {                                                                  \
    bf16x8 bh0 = wbuf[(((L) * 2 + 0) * 4 + (T)) * 64 + lane];        \
    bf16x8 bh1 = wbuf[(((L) * 2 + 1) * 4 + (T)) * 64 + lane];        \
    bf16x8 bl0 = wbuf[1536 + (((L) * 2 + 0) * 4 + (T)) * 64 + lane]; \
    bf16x8 bl1 = wbuf[1536 + (((L) * 2 + 1) * 4 + (T)) * 64 + lane]; \
    f32x4 a_ = {(BIASV), (BIASV), (BIASV), (BIASV)};                 \
    a_ = MFMA(A0h, bh0, a_);                                         \
    a_ = MFMA(A1h, bh1, a_);                                         \
    a_ = MFMA(A0l, bh0, a_);                                         \
    a_ = MFMA(A1l, bh1, a_);                                         \
    a_ = MFMA(A0h, bl0, a_);                                         \
    a_ = MFMA(A1h, bl1, a_);                                         \
    ACC = a_;                                                        \
  }

#define DOLAYER(L)                   \
  DOT(L, 0, bias##L[0], acc0)        \
  DOT(L, 1, bias##L[1], acc1)        \
  DOT(L, 2, bias##L[2], acc2)        \
  DOT(L, 3, bias##L[3], acc3)

// relu(acc) -> per-wave LDS scratch (pitch 68), literal element indices
#define STORE_T(T, A)                                         \
  sc[(4 * lg + 0) * 68 + (T) * 16 + l15] = fmaxf(A[0], 0.f);  \
  sc[(4 * lg + 1) * 68 + (T) * 16 + l15] = fmaxf(A[1], 0.f);  \
  sc[(4 * lg + 2) * 68 + (T) * 16 + l15] = fmaxf(A[2], 0.f);  \
  sc[(4 * lg + 3) * 68 + (T) * 16 + l15] = fmaxf(A[3], 0.f);

#define TRANSITION                                            \
  {                                                           \
    STORE_T(0, acc0)                                          \
    STORE_T(1, acc1)                                          \
    STORE_T(2, acc2)                                          \
    STORE_T(3, acc3)                                          \
    const float* rp = sc + l15 * 68 + lg * 8;                 \
    f32x4 r0 = *(const f32x4*)(rp);                           \
    f32x4 r1 = *(const f32x4*)(rp + 4);                       \
    f32x4 r2 = *(const f32x4*)(rp + 32);                      \
    f32x4 r3 = *(const f32x4*)(rp + 36);                      \
    split8(r0, r1, A0h, A0l);                                 \
    split8(r2, r3, A1h, A1l);                                 \
  }

// epilogue col-tile: relu, guarded store, per-wave BN partials -> LDS (NO atomics)
#define EPI_T(T, A)                                                       \
  {                                                                       \
    float v0 = fmaxf(A[0], 0.f), v1 = fmaxf(A[1], 0.f);                   \
    float v2 = fmaxf(A[2], 0.f), v3 = fmaxf(A[3], 0.f);                   \
    if (active) {                                                         \
      xout[(size_t)(rows0 + 4 * lg + 0) * DDIM + (T) * 16 + l15] = v0;    \
      xout[(size_t)(rows0 + 4 * lg + 1) * DDIM + (T) * 16 + l15] = v1;    \
      xout[(size_t)(rows0 + 4 * lg + 2) * DDIM + (T) * 16 + l15] = v2;    \
      xout[(size_t)(rows0 + 4 * lg + 3) * DDIM + (T) * 16 + l15] = v3;    \
    }                                                                     \
    float vs = (v0 + v1) + (v2 + v3);                                     \
    float vq = ((v0 * v0 + v1 * v1) + (v2 * v2 + v3 * v3));               \
    vs += __shfl_xor(vs, 16); vs += __shfl_xor(vs, 32);                   \
    vq += __shfl_xor(vq, 16); vq += __shfl_xor(vq, 32);                   \
    if (lane < 16) {                                                      \
      bnred[0][wave][(T) * 16 + l15] = vs;                                \
      bnred[1][wave][(T) * 16 + l15] = vq;                                \
    }                                                                     \
  }

// MFMA MLP: wave per 16-row tile; split-bf16 in, f32 accum; block-local BN partials
// partial layout: partial[col * PPITCH + block]  (col 0..63 = sum, 64..127 = sq)
__global__ __launch_bounds__(256) void mlp_kernel(
    const float* __restrict__ xin, float* __restrict__ xout,
    const bf16x8* __restrict__ wbuf,
    const float* __restrict__ b1, const float* __restrict__ b2, const float* __restrict__ b3,
    float* __restrict__ partial) {
  __shared__ float scratch[4][16 * 68];
  __shared__ float bnred[2][4][64];
  const int tid = threadIdx.x;
  const int lane = tid & 63, wave = tid >> 6;
  const int l15 = lane & 15, lg = lane >> 4;
  const int rows0 = blockIdx.x * 64 + wave * 16;
  const bool active = rows0 < N_NODES;
  float* sc = scratch[wave];

  f32x4 acc0 = {0.f, 0.f, 0.f, 0.f}, acc1 = acc0, acc2 = acc0, acc3 = acc0;

  if (active) {
    float bias0[4], bias1[4], bias2[4];
    #pragma unroll
    for (int t = 0; t < 4; ++t) {
      bias0[t] = b1[t * 16 + l15];
      bias1[t] = b2[t * 16 + l15];
      bias2[t] = b3[t * 16 + l15];
    }

    const float* xrow = xin + (size_t)(rows0 + l15) * DDIM;
    bf16x8 A0h, A0l, A1h, A1l;
    {
      f32x4 v0 = *(const f32x4*)(xrow + lg * 8);
      f32x4 v1 = *(const f32x4*)(xrow + lg * 8 + 4);
      f32x4 v2 = *(const f32x4*)(xrow + 32 + lg * 8);
      f32x4 v3 = *(const f32x4*)(xrow + 32 + lg * 8 + 4);
      split8(v0, v1, A0h, A0l);
      split8(v2, v3, A1h, A1l);
    }

    DOLAYER(0)
    TRANSITION
    DOLAYER(1)
    TRANSITION
    DOLAYER(2)
  }

  EPI_T(0, acc0)
  EPI_T(1, acc1)
  EPI_T(2, acc2)
  EPI_T(3, acc3)

  __syncthreads();
  if (tid < 128) {                     // transposed write: partial[col][block]
    int s = tid >> 6, c = tid & 63;
    partial[(size_t)tid * PPITCH + blockIdx.x] =
        (bnred[s][0][c] + bnred[s][1][c]) + (bnred[s][2][c] + bnred[s][3][c]);
  }
}

// wave per stats-row: sum NB contiguous partials -> colsum[row]
__global__ void bn_stats_kernel(const float* __restrict__ partial,
                                float* __restrict__ colsum) {
  int row = blockIdx.x * 4 + (threadIdx.x >> 6);   // 32 blocks x 4 waves = 128 rows
  int lane = threadIdx.x & 63;
  const float* rp = partial + (size_t)row * PPITCH;
  float acc = 0.f;
  for (int i = lane; i < NB; i += 64) acc += rp[i];
  #pragma unroll
  for (int off = 32; off > 0; off >>= 1) acc += __shfl_down(acc, off);
  if (lane == 0) colsum[row] = acc;
}

// BN-apply -> hb (bf16) + pooling; stats computed inline from colsum
__global__ void norm_pool_kernel(const float* __restrict__ x, __bf16* __restrict__ hb,
                                 float* __restrict__ pooled, const int* __restrict__ goff,
                                 const float* __restrict__ colsum, const float* __restrict__ gamma,
                                 const float* __restrict__ beta, int iter) {
  int g = blockIdx.x;
  int lane = threadIdx.x & 63;
  int wave = threadIdx.x >> 6;
  const float invN = 1.0f / N_NODES;
  float mean = colsum[lane] * invN;
  float var = colsum[64 + lane] * invN - mean * mean;
  float inv = 1.0f / sqrtf(var + 1e-5f);
  float gm = gamma[lane] * inv;
  float bt = beta[lane] - mean * gm;   // h = gm*v + bt
  int rbeg = goff[g], rend = goff[g + 1];
  float acc = 0.f;
  for (int r = rbeg + wave; r < rend; r += 4) {
    float v = fmaf(x[(size_t)r * DDIM + lane], gm, bt);
    hb[(size_t)r * DDIM + lane] = (__bf16)v;
    acc += v;                          // pooled keeps full f32 precision
  }
  __shared__ float red[4][64];
  red[wave][lane] = acc;
  __syncthreads();
  if (wave == 0) {
    pooled[(size_t)g * (ITERS * DDIM) + iter * DDIM + lane] =
        red[0][lane] + red[1][lane] + red[2][lane] + red[3][lane];
  }
}

__global__ void classifier_kernel(const float* __restrict__ pooled, const float* __restrict__ Wc,
                                  const float* __restrict__ bc, float* __restrict__ out) {
  int g = blockIdx.x;
  int c = threadIdx.x;
  if (c >= N_CLASSES) return;
  float acc = bc[c];
  #pragma unroll 4
  for (int k = 0; k < ITERS * DDIM; ++k)
    acc = fmaf(pooled[(size_t)g * (ITERS * DDIM) + k], Wc[k * N_CLASSES + c], acc);
  out[(size_t)g * N_CLASSES + c] = acc;
}

extern "C" void kernel_launch(void* const* d_in, const int* in_sizes, int n_in,
                              void* d_out, int out_size, void* d_ws, size_t ws_size,
                              hipStream_t stream) {
  const int*   pkt   = (const int*)d_in[0];
  const int*   src   = (const int*)d_in[1];
  const int*   dst   = (const int*)d_in[2];
  const int*   gids  = (const int*)d_in[3];
  const float* emb   = (const float*)d_in[4];
  const float* eps   = (const float*)d_in[5];
  const float* W1    = (const float*)d_in[6];
  const float* b1    = (const float*)d_in[7];
  const float* W2    = (const float*)d_in[8];
  const float* b2    = (const float*)d_in[9];
  const float* W3    = (const float*)d_in[10];
  const float* b3    = (const float*)d_in[11];
  const float* gamma = (const float*)d_in[12];
  const float* beta  = (const float*)d_in[13];
  const float* Wc    = (const float*)d_in[14];
  const float* bc    = (const float*)d_in[15];
  float* out = (float*)d_out;

  char* p = (char*)d_ws;
  auto alloc = [&](size_t bytes) {
    char* r = p;
    p += (bytes + 255) & ~(size_t)255;
    return r;
  };
  __bf16*   hb      = (__bf16*)alloc((size_t)N_NODES * DDIM * 2);
  float*    x       = (float*)alloc((size_t)N_NODES * DDIM * 4);
  unsigned* ebuf    = (unsigned*)alloc((size_t)N_EDGES * 4);
  int*      csr     = (int*)alloc((size_t)N_EDGES * 4);
  int*      offs    = (int*)alloc((size_t)(N_NODES + 1) * 4);
  int*      boffs   = (int*)alloc((size_t)(NB + 1) * 4);
  int*      bcursor = (int*)alloc((size_t)NB * 4);
  int*      goff    = (int*)alloc((size_t)(N_GRAPHS + 1) * 4);
  float*    pooled  = (float*)alloc((size_t)N_GRAPHS * ITERS * DDIM * 4);
  float*    colsum  = (float*)alloc(128 * 4);
  bf16x8*   wbuf    = (bf16x8*)alloc((size_t)48 * 64 * 16);   // hi + lo fragments
  float*    partial = (float*)alloc((size_t)128 * PPITCH * 4);
  // contiguous zero region: bhist | gcnt
  size_t zbytes = (size_t)NB * 4 + (size_t)N_GRAPHS * 4;
  char*  zbase  = alloc(zbytes);
  int*   bhist  = (int*)zbase;
  int*   gcnt   = bhist + NB;

  hipMemsetAsync(zbase, 0, zbytes, stream);

  embed_kernel<<<(N_NODES * 16 + 255) / 256, 256, 0, stream>>>(pkt, (const float4*)emb,
                                                               (bf16x4*)hb);
  bucket_hist_kernel<<<512, 256, 0, stream>>>(dst, bhist);
  hist_kernel<<<(N_NODES + 255) / 256, 256, 0, stream>>>(gids, gcnt, N_NODES);
  scans_kernel<<<2, 1024, 0, stream>>>(bhist, boffs, bcursor, gcnt, goff);
  partition_kernel<<<NXCD * NCHUNK, 256, 0, stream>>>(src, dst, bcursor, ebuf);
  local_scatter_kernel<<<NB, 256, 0, stream>>>(ebuf, boffs, offs, csr);
  pack_weights_kernel<<<6, 256, 0, stream>>>(W1, W2, W3, wbuf);

  for (int it = 0; it < ITERS; ++it) {
    aggregate_kernel<<<(N_NODES + 31) / 32, 256, 0, stream>>>(hb, offs, csr, eps, x);
    mlp_kernel<<<NB, 256, 0, stream>>>(x, x, wbuf, b1, b2, b3, partial);
    bn_stats_kernel<<<32, 256, 0, stream>>>(partial, colsum);
    norm_pool_kernel<<<N_GRAPHS, 256, 0, stream>>>(x, hb, pooled, goff, colsum, gamma, beta, it);
  }
  classifier_kernel<<<N_GRAPHS, 64, 0, stream>>>(pooled, Wc, bc, out);
}

// Round 13
// 280.648 us; speedup vs baseline: 1.2977x; 1.2977x over previous
//
#include <hip/hip_runtime.h>

#define N_NODES   50000
#define N_EDGES   1600000
#define DDIM      64
#define N_GRAPHS  512
#define N_CLASSES 53
#define ITERS     3
#define NB        782            // ceil(N_NODES/64) buckets of 64 dst nodes
#define NBLK      391            // ceil(N_NODES/128) fused agg+mlp blocks
#define PPITCH    400            // partial row pitch (>= NBLK)
#define NPB       512            // partition blocks (R10 best point)
#define CHUNK     ((N_EDGES + NPB - 1) / NPB)

typedef __bf16 bf16x8 __attribute__((ext_vector_type(8)));
typedef __bf16 bf16x4 __attribute__((ext_vector_type(4)));
typedef float  f32x4  __attribute__((ext_vector_type(4)));

__device__ __forceinline__ float blo16(unsigned w) { return __uint_as_float(w << 16); }
__device__ __forceinline__ float bhi16(unsigned w) { return __uint_as_float(w & 0xffff0000u); }

// hb[node][d] = bf16(emb[pkt[node]][d])
__global__ void embed_kernel(const int* __restrict__ pkt, const float4* __restrict__ emb,
                             bf16x4* __restrict__ hb4) {
  int idx = blockIdx.x * 256 + threadIdx.x;
  if (idx >= N_NODES * 16) return;
  int node = idx >> 4;
  float4 v = emb[(size_t)pkt[node] * 16 + (idx & 15)];
  bf16x4 o;
  o[0] = (__bf16)v.x; o[1] = (__bf16)v.y; o[2] = (__bf16)v.z; o[3] = (__bf16)v.w;
  hb4[idx] = o;
}

// edge-count per 64-node dst bucket, LDS-staged
__global__ void bucket_hist_kernel(const int* __restrict__ dst, int* __restrict__ bhist) {
  __shared__ int lh[NB];
  for (int i = threadIdx.x; i < NB; i += 256) lh[i] = 0;
  __syncthreads();
  int stride = gridDim.x * 256;
  for (int e = blockIdx.x * 256 + threadIdx.x; e < N_EDGES; e += stride)
    atomicAdd(&lh[dst[e] >> 6], 1);
  __syncthreads();
  for (int i = threadIdx.x; i < NB; i += 256)
    if (lh[i]) atomicAdd(&bhist[i], lh[i]);
}

__global__ void hist_kernel(const int* __restrict__ idx, int* __restrict__ counts, int n) {
  int i = blockIdx.x * 256 + threadIdx.x;
  if (i < n) atomicAdd(&counts[idx[i]], 1);
}

// single-block exclusive scan body; offs[n] = total; optional cursor copy
__device__ void scan_body(const int* __restrict__ counts, int* __restrict__ offs,
                          int* __restrict__ cursor, int n) {
  __shared__ int wsum[16];
  __shared__ int carry;
  int tid = threadIdx.x;               // 1024 threads
  if (tid == 0) carry = 0;
  __syncthreads();
  for (int base = 0; base < n; base += 1024) {
    int i = base + tid;
    int v = (i < n) ? counts[i] : 0;
    int x = v;
    #pragma unroll
    for (int off = 1; off < 64; off <<= 1) {
      int y = __shfl_up(x, off);
      if ((tid & 63) >= off) x += y;
    }
    int w = tid >> 6;
    if ((tid & 63) == 63) wsum[w] = x;
    __syncthreads();
    int woff = 0;
    for (int k = 0; k < w; ++k) woff += wsum[k];
    int incl = x + woff + carry;
    if (i < n) {
      offs[i] = incl - v;
      if (cursor) cursor[i] = incl - v;
    }
    __syncthreads();
    if (tid == 1023) carry = incl;
    __syncthreads();
  }
  if (tid == 0) offs[n] = carry;
}

__global__ void scans_kernel(const int* __restrict__ bhist, int* __restrict__ boffs,
                             int* __restrict__ bcursor, const int* __restrict__ gcnt,
                             int* __restrict__ goff) {
  if (blockIdx.x == 0) scan_body(bhist, boffs, bcursor, NB);
  else                 scan_body(gcnt, goff, nullptr, N_GRAPHS);
}

// bucket-partition edges (R10 config): ebuf[pos] = src(16b) | (dst&63)<<16
__global__ void partition_kernel(const int* __restrict__ src, const int* __restrict__ dst,
                                 int* __restrict__ bcursor, unsigned* __restrict__ ebuf) {
  __shared__ int lh[NB];
  __shared__ int lbase[NB];
  for (int i = threadIdx.x; i < NB; i += 256) lh[i] = 0;
  __syncthreads();
  int e0 = blockIdx.x * CHUNK;
  int e1 = min(e0 + CHUNK, N_EDGES);
  for (int e = e0 + (int)threadIdx.x; e < e1; e += 256)
    atomicAdd(&lh[dst[e] >> 6], 1);
  __syncthreads();
  for (int i = threadIdx.x; i < NB; i += 256) {
    int c = lh[i];
    lbase[i] = c ? atomicAdd(&bcursor[i], c) : 0;
    lh[i] = 0;                         // reuse as running cursor
  }
  __syncthreads();
  for (int e = e0 + (int)threadIdx.x; e < e1; e += 256) {
    int d = dst[e];
    int b = d >> 6;
    int pos = lbase[b] + atomicAdd(&lh[b], 1);
    ebuf[pos] = (unsigned)src[e] | ((unsigned)(d & 63) << 16);
  }
}

// block per bucket: per-node offsets (in-block 64-scan) + CSR scatter locally
__global__ __launch_bounds__(256) void local_scatter_kernel(
    const unsigned* __restrict__ ebuf, const int* __restrict__ boffs,
    int* __restrict__ offs, int* __restrict__ csr) {
  __shared__ int cnt[64];
  __shared__ int base[64];
  const int b = blockIdx.x;
  const int tid = threadIdx.x;
  if (tid < 64) cnt[tid] = 0;
  __syncthreads();
  const int ebeg = boffs[b], eend = boffs[b + 1];
  for (int e = ebeg + tid; e < eend; e += 256)
    atomicAdd(&cnt[(ebuf[e] >> 16) & 63u], 1);
  __syncthreads();
  if (tid < 64) {                      // wave 0: exclusive scan of 64 counts
    int v = cnt[tid];
    int x = v;
    #pragma unroll
    for (int off = 1; off < 64; off <<= 1) {
      int y = __shfl_up(x, off);
      if (tid >= off) x += y;
    }
    int excl = ebeg + x - v;
    base[tid] = excl;
    int node = b * 64 + tid;
    if (node < N_NODES) offs[node] = excl;
    cnt[tid] = 0;                      // reuse as running cursor
  }
  __syncthreads();
  for (int e = ebeg + tid; e < eend; e += 256) {
    unsigned p = ebuf[e];
    int j = (p >> 16) & 63u;
    int pos = base[j] + atomicAdd(&cnt[j], 1);
    csr[pos] = (int)(p & 0xFFFFu);
  }
  if (b == NB - 1 && tid == 0) offs[N_NODES] = N_EDGES;
}

// pack W1,W2,W3 into MFMA B-fragment order, SPLIT bf16: hi=bf16(w), lo=bf16(w-hi).
__global__ void pack_weights_kernel(const float* __restrict__ W1, const float* __restrict__ W2,
                                    const float* __restrict__ W3, bf16x8* __restrict__ wbuf) {
  int i = blockIdx.x * 256 + threadIdx.x;
  if (i >= 24 * 64) return;
  int lane = i & 63;
  int frag = i >> 6;
  int t = frag & 3;
  int kc = (frag >> 2) & 1;
  int L = frag >> 3;
  const float* W = (L == 0) ? W1 : ((L == 1) ? W2 : W3);
  int l15 = lane & 15, lg = lane >> 4;
  bf16x8 fh, fl;
  #pragma unroll
  for (int e = 0; e < 8; ++e) {
    int k = kc * 32 + lg * 8 + e;
    float w = W[k * 64 + t * 16 + l15];
    __bf16 hi = (__bf16)w;
    fh[e] = hi;
    fl[e] = (__bf16)(w - (float)hi);
  }
  wbuf[i] = fh;
  wbuf[24 * 64 + i] = fl;
}

__device__ __forceinline__ void split8(const f32x4& v0, const f32x4& v1,
                                       bf16x8& hi, bf16x8& lo) {
  #pragma unroll
  for (int e = 0; e < 4; ++e) {
    __bf16 h0 = (__bf16)v0[e];
    __bf16 h1 = (__bf16)v1[e];
    hi[e] = h0;     lo[e] = (__bf16)(v0[e] - (float)h0);
    hi[4 + e] = h1; lo[4 + e] = (__bf16)(v1[e] - (float)h1);
  }
}

#define MFMA(A, B, C) __builtin_amdgcn_mfma_f32_16x16x32_bf16((A), (B), (C), 0, 0, 0)

#define DOT(L, T, BIASV, ACC)                                        \
  {                                                                  \
    bf16x8 bh0 = wbuf[(((L) * 2 + 0) * 4 + (T)) * 64 + lane];        \
    bf16x8 bh1 = wbuf[(((L) * 2 + 1) * 4 + (T)) * 64 + lane];        \
    bf16x8 bl0 = wbuf[1536 + (((L) * 2 + 0) * 4 + (T)) * 64 + lane]; \
    bf16x8 bl1 = wbuf[1536 + (((L) * 2 + 1) * 4 + (T)) * 64 + lane]; \
    f32x4 a_ = {(BIASV), (BIASV), (BIASV), (BIASV)};                 \
    a_ = MFMA(A0h, bh0, a_);                                         \
    a_ = MFMA(A1h, bh1, a_);                                         \
    a_ = MFMA(A0l, bh0, a_);                                         \
    a_ = MFMA(A1l, bh1, a_);                                         \
    a_ = MFMA(A0h, bl0, a_);                                         \
    a_ = MFMA(A1h, bl1, a_);                                         \
    ACC = a_;                                                        \
  }

#define DOLAYER(L)                   \
  DOT(L, 0, bias##L[0], acc0)        \
  DOT(L, 1, bias##L[1], acc1)        \
  DOT(L, 2, bias##L[2], acc2)        \
  DOT(L, 3, bias##L[3], acc3)

#define STORE_T(T, A)                                         \
  sc[(4 * lg + 0) * 68 + (T) * 16 + l15] = fmaxf(A[0], 0.f);  \
  sc[(4 * lg + 1) * 68 + (T) * 16 + l15] = fmaxf(A[1], 0.f);  \
  sc[(4 * lg + 2) * 68 + (T) * 16 + l15] = fmaxf(A[2], 0.f);  \
  sc[(4 * lg + 3) * 68 + (T) * 16 + l15] = fmaxf(A[3], 0.f);

#define TRANSITION                                            \
  {                                                           \
    STORE_T(0, acc0)                                          \
    STORE_T(1, acc1)                                          \
    STORE_T(2, acc2)                                          \
    STORE_T(3, acc3)                                          \
    const float* rp = sc + l15 * 68 + lg * 8;                 \
    f32x4 r0 = *(const f32x4*)(rp);                           \
    f32x4 r1 = *(const f32x4*)(rp + 4);                       \
    f32x4 r2 = *(const f32x4*)(rp + 32);                      \
    f32x4 r3 = *(const f32x4*)(rp + 36);                      \
    split8(r0, r1, A0h, A0l);                                 \
    split8(r2, r3, A1h, A1l);                                 \
  }

#define EPI_T(T, A)                                                       \
  {                                                                       \
    float v0 = fmaxf(A[0], 0.f), v1 = fmaxf(A[1], 0.f);                   \
    float v2 = fmaxf(A[2], 0.f), v3 = fmaxf(A[3], 0.f);                   \
    if (active) {                                                         \
      xout[(size_t)(rows0 + 4 * lg + 0) * DDIM + (T) * 16 + l15] = v0;    \
      xout[(size_t)(rows0 + 4 * lg + 1) * DDIM + (T) * 16 + l15] = v1;    \
      xout[(size_t)(rows0 + 4 * lg + 2) * DDIM + (T) * 16 + l15] = v2;    \
      xout[(size_t)(rows0 + 4 * lg + 3) * DDIM + (T) * 16 + l15] = v3;    \
    }                                                                     \
    float vs = (v0 + v1) + (v2 + v3);                                     \
    float vq = ((v0 * v0 + v1 * v1) + (v2 * v2 + v3 * v3));               \
    vs += __shfl_xor(vs, 16); vs += __shfl_xor(vs, 32);                   \
    vq += __shfl_xor(vq, 16); vq += __shfl_xor(vq, 32);                   \
    if (lane < 16) {                                                      \
      bnred[0][wave][(T) * 16 + l15] = vs;                                \
      bnred[1][wave][(T) * 16 + l15] = vq;                                \
    }                                                                     \
  }

// FUSED aggregate + MFMA MLP. 512 threads = 8 waves; wave w owns rows
// [blk*128 + w*16, +16): aggregates them into its private 16x68 LDS tile
// (2 passes x 8-lane-groups, dwordx4 gathers), then runs the 3-layer MLP
// reading A-frags from that tile (reused as TRANSITION scratch). No barrier
// until the BN-partial epilogue. Kills x's global round-trip.
__global__ __launch_bounds__(512) void agg_mlp_kernel(
    const __bf16* __restrict__ hb, const int* __restrict__ offs,
    const int* __restrict__ csr, const float* __restrict__ epsp,
    float* __restrict__ xout, const bf16x8* __restrict__ wbuf,
    const float* __restrict__ b1, const float* __restrict__ b2,
    const float* __restrict__ b3, float* __restrict__ partial) {
  __shared__ float xt[8 * 16 * 68];    // 34.8 KB: per-wave agg-out + scratch
  __shared__ float bnred[2][8][64];
  const int tid = threadIdx.x;
  const int lane = tid & 63, wave = tid >> 6;
  const int l15 = lane & 15, lg = lane >> 4;
  const int rows0 = blockIdx.x * 128 + wave * 16;
  const bool active = rows0 < N_NODES; // all-or-nothing per wave (50000 % 16 == 0)
  float* xw = xt + wave * (16 * 68);

  // ---- aggregate phase: x[r] = (1+eps)*hb[r] + sum_u hb[u], r in wave's 16 rows
  {
    const int fl = lane & 7, eg = lane >> 3;
    const uint4* __restrict__ hrow4 = (const uint4*)hb;
    const float ep = 1.0f + epsp[0];
    #pragma unroll
    for (int pass = 0; pass < 2; ++pass) {
      const int node = rows0 + pass * 8 + eg;
      int beg = 0, end = 0;
      if (active) { beg = offs[node]; end = offs[node + 1]; }
      const int deg = end - beg;
      int maxdeg = deg;
      maxdeg = max(maxdeg, __shfl_xor(maxdeg, 8));
      maxdeg = max(maxdeg, __shfl_xor(maxdeg, 16));
      maxdeg = max(maxdeg, __shfl_xor(maxdeg, 32));

      float a0 = 0.f, a1 = 0.f, a2 = 0.f, a3 = 0.f,
            a4 = 0.f, a5 = 0.f, a6 = 0.f, a7 = 0.f;
      if (active) {
        uint4 w = hrow4[(size_t)node * 8 + fl];
        a0 = ep * blo16(w.x); a1 = ep * bhi16(w.x);
        a2 = ep * blo16(w.y); a3 = ep * bhi16(w.y);
        a4 = ep * blo16(w.z); a5 = ep * bhi16(w.z);
        a6 = ep * blo16(w.w); a7 = ep * bhi16(w.w);
      }
      #pragma unroll 4
      for (int it = 0; it < maxdeg; ++it) {
        bool act = it < deg;
        int ci = beg + it;
        ci = (ci < N_EDGES) ? ci : 0;
        int u = csr[ci];
        uint4 w = hrow4[(size_t)u * 8 + fl];
        unsigned m = act ? 0xffffffffu : 0u;
        w.x &= m; w.y &= m; w.z &= m; w.w &= m;
        a0 += blo16(w.x); a1 += bhi16(w.x);
        a2 += blo16(w.y); a3 += bhi16(w.y);
        a4 += blo16(w.z); a5 += bhi16(w.z);
        a6 += blo16(w.w); a7 += bhi16(w.w);
      }
      float* xp = xw + (pass * 8 + eg) * 68 + fl * 8;
      float4 o0 = {a0, a1, a2, a3};
      float4 o1 = {a4, a5, a6, a7};
      *(float4*)xp = o0;
      *(float4*)(xp + 4) = o1;
    }
  }
  // wave-private tile: no __syncthreads needed before MLP.

  f32x4 acc0 = {0.f, 0.f, 0.f, 0.f}, acc1 = acc0, acc2 = acc0, acc3 = acc0;
  if (active) {
    float bias0[4], bias1[4], bias2[4];
    #pragma unroll
    for (int t = 0; t < 4; ++t) {
      bias0[t] = b1[t * 16 + l15];
      bias1[t] = b2[t * 16 + l15];
      bias2[t] = b3[t * 16 + l15];
    }
    float* sc = xw;                    // reuse agg tile as TRANSITION scratch
    bf16x8 A0h, A0l, A1h, A1l;
    {
      const float* rp = xw + l15 * 68 + lg * 8;
      f32x4 r0 = *(const f32x4*)(rp);
      f32x4 r1 = *(const f32x4*)(rp + 4);
      f32x4 r2 = *(const f32x4*)(rp + 32);
      f32x4 r3 = *(const f32x4*)(rp + 36);
      split8(r0, r1, A0h, A0l);
      split8(r2, r3, A1h, A1l);
    }
    DOLAYER(0)
    TRANSITION
    DOLAYER(1)
    TRANSITION
    DOLAYER(2)
  }

  EPI_T(0, acc0)
  EPI_T(1, acc1)
  EPI_T(2, acc2)
  EPI_T(3, acc3)

  __syncthreads();
  if (tid < 128) {                     // transposed: partial[col][block]
    int s = tid >> 6, c = tid & 63;
    float t = 0.f;
    #pragma unroll
    for (int w = 0; w < 8; ++w) t += bnred[s][w][c];
    partial[(size_t)tid * PPITCH + blockIdx.x] = t;
  }
}

// wave per stats-row: sum NBLK contiguous partials -> colsum[row]
__global__ void bn_stats_kernel(const float* __restrict__ partial,
                                float* __restrict__ colsum) {
  int row = blockIdx.x * 4 + (threadIdx.x >> 6);   // 32 blocks x 4 waves = 128 rows
  int lane = threadIdx.x & 63;
  const float* rp = partial + (size_t)row * PPITCH;
  float acc = 0.f;
  for (int i = lane; i < NBLK; i += 64) acc += rp[i];
  #pragma unroll
  for (int off = 32; off > 0; off >>= 1) acc += __shfl_down(acc, off);
  if (lane == 0) colsum[row] = acc;
}

// BN-apply -> hb (bf16) + pooling; stats computed inline from colsum
__global__ void norm_pool_kernel(const float* __restrict__ x, __bf16* __restrict__ hb,
                                 float* __restrict__ pooled, const int* __restrict__ goff,
                                 const float* __restrict__ colsum, const float* __restrict__ gamma,
                                 const float* __restrict__ beta, int iter) {
  int g = blockIdx.x;
  int lane = threadIdx.x & 63;
  int wave = threadIdx.x >> 6;
  const float invN = 1.0f / N_NODES;
  float mean = colsum[lane] * invN;
  float var = colsum[64 + lane] * invN - mean * mean;
  float inv = 1.0f / sqrtf(var + 1e-5f);
  float gm = gamma[lane] * inv;
  float bt = beta[lane] - mean * gm;   // h = gm*v + bt
  int rbeg = goff[g], rend = goff[g + 1];
  float acc = 0.f;
  for (int r = rbeg + wave; r < rend; r += 4) {
    float v = fmaf(x[(size_t)r * DDIM + lane], gm, bt);
    hb[(size_t)r * DDIM + lane] = (__bf16)v;
    acc += v;                          // pooled keeps full f32 precision
  }
  __shared__ float red[4][64];
  red[wave][lane] = acc;
  __syncthreads();
  if (wave == 0) {
    pooled[(size_t)g * (ITERS * DDIM) + iter * DDIM + lane] =
        red[0][lane] + red[1][lane] + red[2][lane] + red[3][lane];
  }
}

__global__ void classifier_kernel(const float* __restrict__ pooled, const float* __restrict__ Wc,
                                  const float* __restrict__ bc, float* __restrict__ out) {
  int g = blockIdx.x;
  int c = threadIdx.x;
  if (c >= N_CLASSES) return;
  float acc = bc[c];
  #pragma unroll 4
  for (int k = 0; k < ITERS * DDIM; ++k)
    acc = fmaf(pooled[(size_t)g * (ITERS * DDIM) + k], Wc[k * N_CLASSES + c], acc);
  out[(size_t)g * N_CLASSES + c] = acc;
}

extern "C" void kernel_launch(void* const* d_in, const int* in_sizes, int n_in,
                              void* d_out, int out_size, void* d_ws, size_t ws_size,
                              hipStream_t stream) {
  const int*   pkt   = (const int*)d_in[0];
  const int*   src   = (const int*)d_in[1];
  const int*   dst   = (const int*)d_in[2];
  const int*   gids  = (const int*)d_in[3];
  const float* emb   = (const float*)d_in[4];
  const float* eps   = (const float*)d_in[5];
  const float* W1    = (const float*)d_in[6];
  const float* b1    = (const float*)d_in[7];
  const float* W2    = (const float*)d_in[8];
  const float* b2    = (const float*)d_in[9];
  const float* W3    = (const float*)d_in[10];
  const float* b3    = (const float*)d_in[11];
  const float* gamma = (const float*)d_in[12];
  const float* beta  = (const float*)d_in[13];
  const float* Wc    = (const float*)d_in[14];
  const float* bc    = (const float*)d_in[15];
  float* out = (float*)d_out;

  char* p = (char*)d_ws;
  auto alloc = [&](size_t bytes) {
    char* r = p;
    p += (bytes + 255) & ~(size_t)255;
    return r;
  };
  __bf16*   hb      = (__bf16*)alloc((size_t)N_NODES * DDIM * 2);
  float*    x       = (float*)alloc((size_t)N_NODES * DDIM * 4);
  unsigned* ebuf    = (unsigned*)alloc((size_t)N_EDGES * 4);
  int*      csr     = (int*)alloc((size_t)N_EDGES * 4);
  int*      offs    = (int*)alloc((size_t)(N_NODES + 1) * 4);
  int*      boffs   = (int*)alloc((size_t)(NB + 1) * 4);
  int*      bcursor = (int*)alloc((size_t)NB * 4);
  int*      goff    = (int*)alloc((size_t)(N_GRAPHS + 1) * 4);
  float*    pooled  = (float*)alloc((size_t)N_GRAPHS * ITERS * DDIM * 4);
  float*    colsum  = (float*)alloc(128 * 4);
  bf16x8*   wbuf    = (bf16x8*)alloc((size_t)48 * 64 * 16);   // hi + lo fragments
  float*    partial = (float*)alloc((size_t)128 * PPITCH * 4);
  // contiguous zero region: bhist | gcnt
  size_t zbytes = (size_t)NB * 4 + (size_t)N_GRAPHS * 4;
  char*  zbase  = alloc(zbytes);
  int*   bhist  = (int*)zbase;
  int*   gcnt   = bhist + NB;

  hipMemsetAsync(zbase, 0, zbytes, stream);

  embed_kernel<<<(N_NODES * 16 + 255) / 256, 256, 0, stream>>>(pkt, (const float4*)emb,
                                                               (bf16x4*)hb);
  bucket_hist_kernel<<<512, 256, 0, stream>>>(dst, bhist);
  hist_kernel<<<(N_NODES + 255) / 256, 256, 0, stream>>>(gids, gcnt, N_NODES);
  scans_kernel<<<2, 1024, 0, stream>>>(bhist, boffs, bcursor, gcnt, goff);
  partition_kernel<<<NPB, 256, 0, stream>>>(src, dst, bcursor, ebuf);
  local_scatter_kernel<<<NB, 256, 0, stream>>>(ebuf, boffs, offs, csr);
  pack_weights_kernel<<<6, 256, 0, stream>>>(W1, W2, W3, wbuf);

  for (int it = 0; it < ITERS; ++it) {
    agg_mlp_kernel<<<NBLK, 512, 0, stream>>>(hb, offs, csr, eps, x, wbuf,
                                             b1, b2, b3, partial);
    bn_stats_kernel<<<32, 256, 0, stream>>>(partial, colsum);
    norm_pool_kernel<<<N_GRAPHS, 256, 0, stream>>>(x, hb, pooled, goff, colsum, gamma, beta, it);
  }
  classifier_kernel<<<N_GRAPHS, 64, 0, stream>>>(pooled, Wc, bc, out);
}

// Round 14
// 266.538 us; speedup vs baseline: 1.3664x; 1.0529x over previous
//
#include <hip/hip_runtime.h>

#define N_NODES   50000
#define N_EDGES   1600000
#define DDIM      64
#define N_GRAPHS  512
#define N_CLASSES 53
#define ITERS     3
#define NB        782            // ceil(N_NODES/64) buckets of 64 dst nodes
#define NBLK      391            // ceil(N_NODES/128) fused agg+mlp blocks
#define PPITCH    400            // partial row pitch (>= NBLK)
#define NPB       128            // partition blocks (1024 threads each)
#define CHUNK     ((N_EDGES + NPB - 1) / NPB)
#define NZERO     (NB + N_GRAPHS)

typedef __bf16 bf16x8 __attribute__((ext_vector_type(8)));
typedef __bf16 bf16x4 __attribute__((ext_vector_type(4)));
typedef float  f32x4  __attribute__((ext_vector_type(4)));

__device__ __forceinline__ float blo16(unsigned w) { return __uint_as_float(w << 16); }
__device__ __forceinline__ float bhi16(unsigned w) { return __uint_as_float(w & 0xffff0000u); }

// hb[node][d] = bf16(emb[pkt[node]][d]); block 0 also zeroes the hist counters
// (replaces a hipMemsetAsync that cost ~41us/replay as a graph fill dispatch)
__global__ void embed_kernel(const int* __restrict__ pkt, const float4* __restrict__ emb,
                             bf16x4* __restrict__ hb4, int* __restrict__ zreg) {
  if (blockIdx.x == 0) {
    for (int i = threadIdx.x; i < NZERO; i += 256) zreg[i] = 0;
  }
  int idx = blockIdx.x * 256 + threadIdx.x;
  if (idx >= N_NODES * 16) return;
  int node = idx >> 4;
  float4 v = emb[(size_t)pkt[node] * 16 + (idx & 15)];
  bf16x4 o;
  o[0] = (__bf16)v.x; o[1] = (__bf16)v.y; o[2] = (__bf16)v.z; o[3] = (__bf16)v.w;
  hb4[idx] = o;
}

// edge-count per 64-node dst bucket, LDS-staged
__global__ void bucket_hist_kernel(const int* __restrict__ dst, int* __restrict__ bhist) {
  __shared__ int lh[NB];
  for (int i = threadIdx.x; i < NB; i += 256) lh[i] = 0;
  __syncthreads();
  int stride = gridDim.x * 256;
  for (int e = blockIdx.x * 256 + threadIdx.x; e < N_EDGES; e += stride)
    atomicAdd(&lh[dst[e] >> 6], 1);
  __syncthreads();
  for (int i = threadIdx.x; i < NB; i += 256)
    if (lh[i]) atomicAdd(&bhist[i], lh[i]);
}

__global__ void hist_kernel(const int* __restrict__ idx, int* __restrict__ counts, int n) {
  int i = blockIdx.x * 256 + threadIdx.x;
  if (i < n) atomicAdd(&counts[idx[i]], 1);
}

// single-block exclusive scan body; offs[n] = total; optional cursor copy
__device__ void scan_body(const int* __restrict__ counts, int* __restrict__ offs,
                          int* __restrict__ cursor, int n) {
  __shared__ int wsum[16];
  __shared__ int carry;
  int tid = threadIdx.x;               // 1024 threads
  if (tid == 0) carry = 0;
  __syncthreads();
  for (int base = 0; base < n; base += 1024) {
    int i = base + tid;
    int v = (i < n) ? counts[i] : 0;
    int x = v;
    #pragma unroll
    for (int off = 1; off < 64; off <<= 1) {
      int y = __shfl_up(x, off);
      if ((tid & 63) >= off) x += y;
    }
    int w = tid >> 6;
    if ((tid & 63) == 63) wsum[w] = x;
    __syncthreads();
    int woff = 0;
    for (int k = 0; k < w; ++k) woff += wsum[k];
    int incl = x + woff + carry;
    if (i < n) {
      offs[i] = incl - v;
      if (cursor) cursor[i] = incl - v;
    }
    __syncthreads();
    if (tid == 1023) carry = incl;
    __syncthreads();
  }
  if (tid == 0) offs[n] = carry;
}

__global__ void scans_kernel(const int* __restrict__ bhist, int* __restrict__ boffs,
                             int* __restrict__ bcursor, const int* __restrict__ gcnt,
                             int* __restrict__ goff) {
  if (blockIdx.x == 0) scan_body(bhist, boffs, bcursor, NB);
  else                 scan_body(gcnt, goff, nullptr, N_GRAPHS);
}

// bucket-partition: 128 blocks x 1024 threads -> ~16-edge (64B) runs per
// bucket per block: one dirty line per run (kills write amplification) while
// keeping 2048 waves of latency-hiding.
__global__ __launch_bounds__(1024) void partition_kernel(
    const int* __restrict__ src, const int* __restrict__ dst,
    int* __restrict__ bcursor, unsigned* __restrict__ ebuf) {
  __shared__ int lh[NB];
  __shared__ int lbase[NB];
  for (int i = threadIdx.x; i < NB; i += 1024) lh[i] = 0;
  __syncthreads();
  int e0 = blockIdx.x * CHUNK;
  int e1 = min(e0 + CHUNK, N_EDGES);
  for (int e = e0 + (int)threadIdx.x; e < e1; e += 1024)
    atomicAdd(&lh[dst[e] >> 6], 1);
  __syncthreads();
  for (int i = threadIdx.x; i < NB; i += 1024) {
    int c = lh[i];
    lbase[i] = c ? atomicAdd(&bcursor[i], c) : 0;
    lh[i] = 0;                         // reuse as running cursor
  }
  __syncthreads();
  for (int e = e0 + (int)threadIdx.x; e < e1; e += 1024) {
    int d = dst[e];
    int b = d >> 6;
    int pos = lbase[b] + atomicAdd(&lh[b], 1);
    ebuf[pos] = (unsigned)src[e] | ((unsigned)(d & 63) << 16);
  }
}

// block per bucket: per-node offsets (in-block 64-scan) + CSR scatter locally
__global__ __launch_bounds__(256) void local_scatter_kernel(
    const unsigned* __restrict__ ebuf, const int* __restrict__ boffs,
    int* __restrict__ offs, int* __restrict__ csr) {
  __shared__ int cnt[64];
  __shared__ int base[64];
  const int b = blockIdx.x;
  const int tid = threadIdx.x;
  if (tid < 64) cnt[tid] = 0;
  __syncthreads();
  const int ebeg = boffs[b], eend = boffs[b + 1];
  for (int e = ebeg + tid; e < eend; e += 256)
    atomicAdd(&cnt[(ebuf[e] >> 16) & 63u], 1);
  __syncthreads();
  if (tid < 64) {                      // wave 0: exclusive scan of 64 counts
    int v = cnt[tid];
    int x = v;
    #pragma unroll
    for (int off = 1; off < 64; off <<= 1) {
      int y = __shfl_up(x, off);
      if (tid >= off) x += y;
    }
    int excl = ebeg + x - v;
    base[tid] = excl;
    int node = b * 64 + tid;
    if (node < N_NODES) offs[node] = excl;
    cnt[tid] = 0;                      // reuse as running cursor
  }
  __syncthreads();
  for (int e = ebeg + tid; e < eend; e += 256) {
    unsigned p = ebuf[e];
    int j = (p >> 16) & 63u;
    int pos = base[j] + atomicAdd(&cnt[j], 1);
    csr[pos] = (int)(p & 0xFFFFu);
  }
  if (b == NB - 1 && tid == 0) offs[N_NODES] = N_EDGES;
}

// pack W1,W2,W3 into MFMA B-fragment order, SPLIT bf16: hi=bf16(w), lo=bf16(w-hi).
__global__ void pack_weights_kernel(const float* __restrict__ W1, const float* __restrict__ W2,
                                    const float* __restrict__ W3, bf16x8* __restrict__ wbuf) {
  int i = blockIdx.x * 256 + threadIdx.x;
  if (i >= 24 * 64) return;
  int lane = i & 63;
  int frag = i >> 6;
  int t = frag & 3;
  int kc = (frag >> 2) & 1;
  int L = frag >> 3;
  const float* W = (L == 0) ? W1 : ((L == 1) ? W2 : W3);
  int l15 = lane & 15, lg = lane >> 4;
  bf16x8 fh, fl;
  #pragma unroll
  for (int e = 0; e < 8; ++e) {
    int k = kc * 32 + lg * 8 + e;
    float w = W[k * 64 + t * 16 + l15];
    __bf16 hi = (__bf16)w;
    fh[e] = hi;
    fl[e] = (__bf16)(w - (float)hi);
  }
  wbuf[i] = fh;
  wbuf[24 * 64 + i] = fl;
}

__device__ __forceinline__ void split8(const f32x4& v0, const f32x4& v1,
                                       bf16x8& hi, bf16x8& lo) {
  #pragma unroll
  for (int e = 0; e < 4; ++e) {
    __bf16 h0 = (__bf16)v0[e];
    __bf16 h1 = (__bf16)v1[e];
    hi[e] = h0;     lo[e] = (__bf16)(v0[e] - (float)h0);
    hi[4 + e] = h1; lo[4 + e] = (__bf16)(v1[e] - (float)h1);
  }
}

#define MFMA(A, B, C) __builtin_amdgcn_mfma_f32_16x16x32_bf16((A), (B), (C), 0, 0, 0)

#define DOT(L, T, BIASV, ACC)                                        \
  {                                                                  \
    bf16x8 bh0 = wbuf[(((L) * 2 + 0) * 4 + (T)) * 64 + lane];        \
    bf16x8 bh1 = wbuf[(((L) * 2 + 1) * 4 + (T)) * 64 + lane];        \
    bf16x8 bl0 = wbuf[1536 + (((L) * 2 + 0) * 4 + (T)) * 64 + lane]; \
    bf16x8 bl1 = wbuf[1536 + (((L) * 2 + 1) * 4 + (T)) * 64 + lane]; \
    f32x4 a_ = {(BIASV), (BIASV), (BIASV), (BIASV)};                 \
    a_ = MFMA(A0h, bh0, a_);                                         \
    a_ = MFMA(A1h, bh1, a_);                                         \
    a_ = MFMA(A0l, bh0, a_);                                         \
    a_ = MFMA(A1l, bh1, a_);                                         \
    a_ = MFMA(A0h, bl0, a_);                                         \
    a_ = MFMA(A1h, bl1, a_);                                         \
    ACC = a_;                                                        \
  }

#define DOLAYER(L)                   \
  DOT(L, 0, bias##L[0], acc0)        \
  DOT(L, 1, bias##L[1], acc1)        \
  DOT(L, 2, bias##L[2], acc2)        \
  DOT(L, 3, bias##L[3], acc3)

#define STORE_T(T, A)                                         \
  sc[(4 * lg + 0) * 68 + (T) * 16 + l15] = fmaxf(A[0], 0.f);  \
  sc[(4 * lg + 1) * 68 + (T) * 16 + l15] = fmaxf(A[1], 0.f);  \
  sc[(4 * lg + 2) * 68 + (T) * 16 + l15] = fmaxf(A[2], 0.f);  \
  sc[(4 * lg + 3) * 68 + (T) * 16 + l15] = fmaxf(A[3], 0.f);

#define TRANSITION                                            \
  {                                                           \
    STORE_T(0, acc0)                                          \
    STORE_T(1, acc1)                                          \
    STORE_T(2, acc2)                                          \
    STORE_T(3, acc3)                                          \
    const float* rp = sc + l15 * 68 + lg * 8;                 \
    f32x4 r0 = *(const f32x4*)(rp);                           \
    f32x4 r1 = *(const f32x4*)(rp + 4);                       \
    f32x4 r2 = *(const f32x4*)(rp + 32);                      \
    f32x4 r3 = *(const f32x4*)(rp + 36);                      \
    split8(r0, r1, A0h, A0l);                                 \
    split8(r2, r3, A1h, A1l);                                 \
  }

#define EPI_T(T, A)                                                       \
  {                                                                       \
    float v0 = fmaxf(A[0], 0.f), v1 = fmaxf(A[1], 0.f);                   \
    float v2 = fmaxf(A[2], 0.f), v3 = fmaxf(A[3], 0.f);                   \
    if (active) {                                                         \
      xout[(size_t)(rows0 + 4 * lg + 0) * DDIM + (T) * 16 + l15] = v0;    \
      xout[(size_t)(rows0 + 4 * lg + 1) * DDIM + (T) * 16 + l15] = v1;    \
      xout[(size_t)(rows0 + 4 * lg + 2) * DDIM + (T) * 16 + l15] = v2;    \
      xout[(size_t)(rows0 + 4 * lg + 3) * DDIM + (T) * 16 + l15] = v3;    \
    }                                                                     \
    float vs = (v0 + v1) + (v2 + v3);                                     \
    float vq = ((v0 * v0 + v1 * v1) + (v2 * v2 + v3 * v3));               \
    vs += __shfl_xor(vs, 16); vs += __shfl_xor(vs, 32);                   \
    vq += __shfl_xor(vq, 16); vq += __shfl_xor(vq, 32);                   \
    if (lane < 16) {                                                      \
      bnred[0][wave][(T) * 16 + l15] = vs;                                \
      bnred[1][wave][(T) * 16 + l15] = vq;                                \
    }                                                                     \
  }

// FUSED aggregate + MFMA MLP (R13 structure, unchanged)
__global__ __launch_bounds__(512) void agg_mlp_kernel(
    const __bf16* __restrict__ hb, const int* __restrict__ offs,
    const int* __restrict__ csr, const float* __restrict__ epsp,
    float* __restrict__ xout, const bf16x8* __restrict__ wbuf,
    const float* __restrict__ b1, const float* __restrict__ b2,
    const float* __restrict__ b3, float* __restrict__ partial) {
  __shared__ float xt[8 * 16 * 68];    // 34.8 KB: per-wave agg-out + scratch
  __shared__ float bnred[2][8][64];
  const int tid = threadIdx.x;
  const int lane = tid & 63, wave = tid >> 6;
  const int l15 = lane & 15, lg = lane >> 4;
  const int rows0 = blockIdx.x * 128 + wave * 16;
  const bool active = rows0 < N_NODES; // all-or-nothing per wave (50000 % 16 == 0)
  float* xw = xt + wave * (16 * 68);

  // ---- aggregate phase
  {
    const int fl = lane & 7, eg = lane >> 3;
    const uint4* __restrict__ hrow4 = (const uint4*)hb;
    const float ep = 1.0f + epsp[0];
    #pragma unroll
    for (int pass = 0; pass < 2; ++pass) {
      const int node = rows0 + pass * 8 + eg;
      int beg = 0, end = 0;
      if (active) { beg = offs[node]; end = offs[node + 1]; }
      const int deg = end - beg;
      int maxdeg = deg;
      maxdeg = max(maxdeg, __shfl_xor(maxdeg, 8));
      maxdeg = max(maxdeg, __shfl_xor(maxdeg, 16));
      maxdeg = max(maxdeg, __shfl_xor(maxdeg, 32));

      float a0 = 0.f, a1 = 0.f, a2 = 0.f, a3 = 0.f,
            a4 = 0.f, a5 = 0.f, a6 = 0.f, a7 = 0.f;
      if (active) {
        uint4 w = hrow4[(size_t)node * 8 + fl];
        a0 = ep * blo16(w.x); a1 = ep * bhi16(w.x);
        a2 = ep * blo16(w.y); a3 = ep * bhi16(w.y);
        a4 = ep * blo16(w.z); a5 = ep * bhi16(w.z);
        a6 = ep * blo16(w.w); a7 = ep * bhi16(w.w);
      }
      #pragma unroll 4
      for (int it = 0; it < maxdeg; ++it) {
        bool act = it < deg;
        int ci = beg + it;
        ci = (ci < N_EDGES) ? ci : 0;
        int u = csr[ci];
        uint4 w = hrow4[(size_t)u * 8 + fl];
        unsigned m = act ? 0xffffffffu : 0u;
        w.x &= m; w.y &= m; w.z &= m; w.w &= m;
        a0 += blo16(w.x); a1 += bhi16(w.x);
        a2 += blo16(w.y); a3 += bhi16(w.y);
        a4 += blo16(w.z); a5 += bhi16(w.z);
        a6 += blo16(w.w); a7 += bhi16(w.w);
      }
      float* xp = xw + (pass * 8 + eg) * 68 + fl * 8;
      float4 o0 = {a0, a1, a2, a3};
      float4 o1 = {a4, a5, a6, a7};
      *(float4*)xp = o0;
      *(float4*)(xp + 4) = o1;
    }
  }
  // wave-private tile: no __syncthreads needed before MLP.

  f32x4 acc0 = {0.f, 0.f, 0.f, 0.f}, acc1 = acc0, acc2 = acc0, acc3 = acc0;
  if (active) {
    float bias0[4], bias1[4], bias2[4];
    #pragma unroll
    for (int t = 0; t < 4; ++t) {
      bias0[t] = b1[t * 16 + l15];
      bias1[t] = b2[t * 16 + l15];
      bias2[t] = b3[t * 16 + l15];
    }
    float* sc = xw;                    // reuse agg tile as TRANSITION scratch
    bf16x8 A0h, A0l, A1h, A1l;
    {
      const float* rp = xw + l15 * 68 + lg * 8;
      f32x4 r0 = *(const f32x4*)(rp);
      f32x4 r1 = *(const f32x4*)(rp + 4);
      f32x4 r2 = *(const f32x4*)(rp + 32);
      f32x4 r3 = *(const f32x4*)(rp + 36);
      split8(r0, r1, A0h, A0l);
      split8(r2, r3, A1h, A1l);
    }
    DOLAYER(0)
    TRANSITION
    DOLAYER(1)
    TRANSITION
    DOLAYER(2)
  }

  EPI_T(0, acc0)
  EPI_T(1, acc1)
  EPI_T(2, acc2)
  EPI_T(3, acc3)

  __syncthreads();
  if (tid < 128) {                     // transposed: partial[col][block]
    int s = tid >> 6, c = tid & 63;
    float t = 0.f;
    #pragma unroll
    for (int w = 0; w < 8; ++w) t += bnred[s][w][c];
    partial[(size_t)tid * PPITCH + blockIdx.x] = t;
  }
}

// wave per stats-row: sum NBLK contiguous partials -> colsum[row]
__global__ void bn_stats_kernel(const float* __restrict__ partial,
                                float* __restrict__ colsum) {
  int row = blockIdx.x * 4 + (threadIdx.x >> 6);   // 32 blocks x 4 waves = 128 rows
  int lane = threadIdx.x & 63;
  const float* rp = partial + (size_t)row * PPITCH;
  float acc = 0.f;
  for (int i = lane; i < NBLK; i += 64) acc += rp[i];
  #pragma unroll
  for (int off = 32; off > 0; off >>= 1) acc += __shfl_down(acc, off);
  if (lane == 0) colsum[row] = acc;
}

// BN-apply -> hb (bf16) + pooling; stats computed inline from colsum
__global__ void norm_pool_kernel(const float* __restrict__ x, __bf16* __restrict__ hb,
                                 float* __restrict__ pooled, const int* __restrict__ goff,
                                 const float* __restrict__ colsum, const float* __restrict__ gamma,
                                 const float* __restrict__ beta, int iter) {
  int g = blockIdx.x;
  int lane = threadIdx.x & 63;
  int wave = threadIdx.x >> 6;
  const float invN = 1.0f / N_NODES;
  float mean = colsum[lane] * invN;
  float var = colsum[64 + lane] * invN - mean * mean;
  float inv = 1.0f / sqrtf(var + 1e-5f);
  float gm = gamma[lane] * inv;
  float bt = beta[lane] - mean * gm;   // h = gm*v + bt
  int rbeg = goff[g], rend = goff[g + 1];
  float acc = 0.f;
  for (int r = rbeg + wave; r < rend; r += 4) {
    float v = fmaf(x[(size_t)r * DDIM + lane], gm, bt);
    hb[(size_t)r * DDIM + lane] = (__bf16)v;
    acc += v;                          // pooled keeps full f32 precision
  }
  __shared__ float red[4][64];
  red[wave][lane] = acc;
  __syncthreads();
  if (wave == 0) {
    pooled[(size_t)g * (ITERS * DDIM) + iter * DDIM + lane] =
        red[0][lane] + red[1][lane] + red[2][lane] + red[3][lane];
  }
}

__global__ void classifier_kernel(const float* __restrict__ pooled, const float* __restrict__ Wc,
                                  const float* __restrict__ bc, float* __restrict__ out) {
  int g = blockIdx.x;
  int c = threadIdx.x;
  if (c >= N_CLASSES) return;
  float acc = bc[c];
  #pragma unroll 4
  for (int k = 0; k < ITERS * DDIM; ++k)
    acc = fmaf(pooled[(size_t)g * (ITERS * DDIM) + k], Wc[k * N_CLASSES + c], acc);
  out[(size_t)g * N_CLASSES + c] = acc;
}

extern "C" void kernel_launch(void* const* d_in, const int* in_sizes, int n_in,
                              void* d_out, int out_size, void* d_ws, size_t ws_size,
                              hipStream_t stream) {
  const int*   pkt   = (const int*)d_in[0];
  const int*   src   = (const int*)d_in[1];
  const int*   dst   = (const int*)d_in[2];
  const int*   gids  = (const int*)d_in[3];
  const float* emb   = (const float*)d_in[4];
  const float* eps   = (const float*)d_in[5];
  const float* W1    = (const float*)d_in[6];
  const float* b1    = (const float*)d_in[7];
  const float* W2    = (const float*)d_in[8];
  const float* b2    = (const float*)d_in[9];
  const float* W3    = (const float*)d_in[10];
  const float* b3    = (const float*)d_in[11];
  const float* gamma = (const float*)d_in[12];
  const float* beta  = (const float*)d_in[13];
  const float* Wc    = (const float*)d_in[14];
  const float* bc    = (const float*)d_in[15];
  float* out = (float*)d_out;

  char* p = (char*)d_ws;
  auto alloc = [&](size_t bytes) {
    char* r = p;
    p += (bytes + 255) & ~(size_t)255;
    return r;
  };
  __bf16*   hb      = (__bf16*)alloc((size_t)N_NODES * DDIM * 2);
  float*    x       = (float*)alloc((size_t)N_NODES * DDIM * 4);
  unsigned* ebuf    = (unsigned*)alloc((size_t)N_EDGES * 4);
  int*      csr     = (int*)alloc((size_t)N_EDGES * 4);
  int*      offs    = (int*)alloc((size_t)(N_NODES + 1) * 4);
  int*      boffs   = (int*)alloc((size_t)(NB + 1) * 4);
  int*      bcursor = (int*)alloc((size_t)NB * 4);
  int*      goff    = (int*)alloc((size_t)(N_GRAPHS + 1) * 4);
  float*    pooled  = (float*)alloc((size_t)N_GRAPHS * ITERS * DDIM * 4);
  float*    colsum  = (float*)alloc(128 * 4);
  bf16x8*   wbuf    = (bf16x8*)alloc((size_t)48 * 64 * 16);   // hi + lo fragments
  float*    partial = (float*)alloc((size_t)128 * PPITCH * 4);
  // contiguous zero region: bhist | gcnt  (zeroed by embed_kernel block 0)
  int*   zreg  = (int*)alloc((size_t)NZERO * 4);
  int*   bhist = zreg;
  int*   gcnt  = bhist + NB;

  embed_kernel<<<(N_NODES * 16 + 255) / 256, 256, 0, stream>>>(pkt, (const float4*)emb,
                                                               (bf16x4*)hb, zreg);
  bucket_hist_kernel<<<512, 256, 0, stream>>>(dst, bhist);
  hist_kernel<<<(N_NODES + 255) / 256, 256, 0, stream>>>(gids, gcnt, N_NODES);
  scans_kernel<<<2, 1024, 0, stream>>>(bhist, boffs, bcursor, gcnt, goff);
  partition_kernel<<<NPB, 1024, 0, stream>>>(src, dst, bcursor, ebuf);
  local_scatter_kernel<<<NB, 256, 0, stream>>>(ebuf, boffs, offs, csr);
  pack_weights_kernel<<<6, 256, 0, stream>>>(W1, W2, W3, wbuf);

  for (int it = 0; it < ITERS; ++it) {
    agg_mlp_kernel<<<NBLK, 512, 0, stream>>>(hb, offs, csr, eps, x, wbuf,
                                             b1, b2, b3, partial);
    bn_stats_kernel<<<32, 256, 0, stream>>>(partial, colsum);
    norm_pool_kernel<<<N_GRAPHS, 256, 0, stream>>>(x, hb, pooled, goff, colsum, gamma, beta, it);
  }
  classifier_kernel<<<N_GRAPHS, 64, 0, stream>>>(pooled, Wc, bc, out);
}

// Round 15
// 240.892 us; speedup vs baseline: 1.5118x; 1.1065x over previous
//
#include <hip/hip_runtime.h>

#define N_NODES   50000
#define N_EDGES   1600000
#define DDIM      64
#define N_GRAPHS  512
#define N_CLASSES 53
#define ITERS     3
#define NB        782            // ceil(N_NODES/64) buckets of 64 dst nodes
#define NBLK      391            // ceil(N_NODES/128) fused agg+mlp blocks
#define PPITCH    400            // partial row pitch (>= NBLK)
#define NPB       128            // partition blocks (1024 threads each)
#define CHUNK     ((N_EDGES + NPB - 1) / NPB)
#define NZERO     (NB + N_GRAPHS)

typedef __bf16 bf16x8 __attribute__((ext_vector_type(8)));
typedef __bf16 bf16x4 __attribute__((ext_vector_type(4)));
typedef float  f32x4  __attribute__((ext_vector_type(4)));

__device__ __forceinline__ float blo16(unsigned w) { return __uint_as_float(w << 16); }
__device__ __forceinline__ float bhi16(unsigned w) { return __uint_as_float(w & 0xffff0000u); }

// hb[node][d] = bf16(emb[pkt[node]][d]); block 0 zeroes hist counters and
// writes the identity affine (gm=1, bt=0) used by iteration 0.
__global__ void embed_kernel(const int* __restrict__ pkt, const float4* __restrict__ emb,
                             bf16x4* __restrict__ hb4, int* __restrict__ zreg,
                             float* __restrict__ gmbt_id) {
  if (blockIdx.x == 0) {
    for (int i = threadIdx.x; i < NZERO; i += 256) zreg[i] = 0;
    if (threadIdx.x < 128) gmbt_id[threadIdx.x] = (threadIdx.x < 64) ? 1.0f : 0.0f;
  }
  int idx = blockIdx.x * 256 + threadIdx.x;
  if (idx >= N_NODES * 16) return;
  int node = idx >> 4;
  float4 v = emb[(size_t)pkt[node] * 16 + (idx & 15)];
  bf16x4 o;
  o[0] = (__bf16)v.x; o[1] = (__bf16)v.y; o[2] = (__bf16)v.z; o[3] = (__bf16)v.w;
  hb4[idx] = o;
}

// edge-count per 64-node dst bucket, LDS-staged
__global__ void bucket_hist_kernel(const int* __restrict__ dst, int* __restrict__ bhist) {
  __shared__ int lh[NB];
  for (int i = threadIdx.x; i < NB; i += 256) lh[i] = 0;
  __syncthreads();
  int stride = gridDim.x * 256;
  for (int e = blockIdx.x * 256 + threadIdx.x; e < N_EDGES; e += stride)
    atomicAdd(&lh[dst[e] >> 6], 1);
  __syncthreads();
  for (int i = threadIdx.x; i < NB; i += 256)
    if (lh[i]) atomicAdd(&bhist[i], lh[i]);
}

__global__ void hist_kernel(const int* __restrict__ idx, int* __restrict__ counts, int n) {
  int i = blockIdx.x * 256 + threadIdx.x;
  if (i < n) atomicAdd(&counts[idx[i]], 1);
}

// single-block exclusive scan body; offs[n] = total; optional cursor copy
__device__ void scan_body(const int* __restrict__ counts, int* __restrict__ offs,
                          int* __restrict__ cursor, int n) {
  __shared__ int wsum[16];
  __shared__ int carry;
  int tid = threadIdx.x;               // 1024 threads
  if (tid == 0) carry = 0;
  __syncthreads();
  for (int base = 0; base < n; base += 1024) {
    int i = base + tid;
    int v = (i < n) ? counts[i] : 0;
    int x = v;
    #pragma unroll
    for (int off = 1; off < 64; off <<= 1) {
      int y = __shfl_up(x, off);
      if ((tid & 63) >= off) x += y;
    }
    int w = tid >> 6;
    if ((tid & 63) == 63) wsum[w] = x;
    __syncthreads();
    int woff = 0;
    for (int k = 0; k < w; ++k) woff += wsum[k];
    int incl = x + woff + carry;
    if (i < n) {
      offs[i] = incl - v;
      if (cursor) cursor[i] = incl - v;
    }
    __syncthreads();
    if (tid == 1023) carry = incl;
    __syncthreads();
  }
  if (tid == 0) offs[n] = carry;
}

__global__ void scans_kernel(const int* __restrict__ bhist, int* __restrict__ boffs,
                             int* __restrict__ bcursor, const int* __restrict__ gcnt,
                             int* __restrict__ goff) {
  if (blockIdx.x == 0) scan_body(bhist, boffs, bcursor, NB);
  else                 scan_body(gcnt, goff, nullptr, N_GRAPHS);
}

// bucket-partition: 128 blocks x 1024 threads (R14 best point)
__global__ __launch_bounds__(1024) void partition_kernel(
    const int* __restrict__ src, const int* __restrict__ dst,
    int* __restrict__ bcursor, unsigned* __restrict__ ebuf) {
  __shared__ int lh[NB];
  __shared__ int lbase[NB];
  for (int i = threadIdx.x; i < NB; i += 1024) lh[i] = 0;
  __syncthreads();
  int e0 = blockIdx.x * CHUNK;
  int e1 = min(e0 + CHUNK, N_EDGES);
  for (int e = e0 + (int)threadIdx.x; e < e1; e += 1024)
    atomicAdd(&lh[dst[e] >> 6], 1);
  __syncthreads();
  for (int i = threadIdx.x; i < NB; i += 1024) {
    int c = lh[i];
    lbase[i] = c ? atomicAdd(&bcursor[i], c) : 0;
    lh[i] = 0;                         // reuse as running cursor
  }
  __syncthreads();
  for (int e = e0 + (int)threadIdx.x; e < e1; e += 1024) {
    int d = dst[e];
    int b = d >> 6;
    int pos = lbase[b] + atomicAdd(&lh[b], 1);
    ebuf[pos] = (unsigned)src[e] | ((unsigned)(d & 63) << 16);
  }
}

// block per bucket: per-node offsets (in-block 64-scan) + CSR scatter locally
__global__ __launch_bounds__(256) void local_scatter_kernel(
    const unsigned* __restrict__ ebuf, const int* __restrict__ boffs,
    int* __restrict__ offs, int* __restrict__ csr) {
  __shared__ int cnt[64];
  __shared__ int base[64];
  const int b = blockIdx.x;
  const int tid = threadIdx.x;
  if (tid < 64) cnt[tid] = 0;
  __syncthreads();
  const int ebeg = boffs[b], eend = boffs[b + 1];
  for (int e = ebeg + tid; e < eend; e += 256)
    atomicAdd(&cnt[(ebuf[e] >> 16) & 63u], 1);
  __syncthreads();
  if (tid < 64) {                      // wave 0: exclusive scan of 64 counts
    int v = cnt[tid];
    int x = v;
    #pragma unroll
    for (int off = 1; off < 64; off <<= 1) {
      int y = __shfl_up(x, off);
      if (tid >= off) x += y;
    }
    int excl = ebeg + x - v;
    base[tid] = excl;
    int node = b * 64 + tid;
    if (node < N_NODES) offs[node] = excl;
    cnt[tid] = 0;                      // reuse as running cursor
  }
  __syncthreads();
  for (int e = ebeg + tid; e < eend; e += 256) {
    unsigned p = ebuf[e];
    int j = (p >> 16) & 63u;
    int pos = base[j] + atomicAdd(&cnt[j], 1);
    csr[pos] = (int)(p & 0xFFFFu);
  }
  if (b == NB - 1 && tid == 0) offs[N_NODES] = N_EDGES;
}

// pack W1,W2,W3 into MFMA B-fragment order, SPLIT bf16: hi=bf16(w), lo=bf16(w-hi).
__global__ void pack_weights_kernel(const float* __restrict__ W1, const float* __restrict__ W2,
                                    const float* __restrict__ W3, bf16x8* __restrict__ wbuf) {
  int i = blockIdx.x * 256 + threadIdx.x;
  if (i >= 24 * 64) return;
  int lane = i & 63;
  int frag = i >> 6;
  int t = frag & 3;
  int kc = (frag >> 2) & 1;
  int L = frag >> 3;
  const float* W = (L == 0) ? W1 : ((L == 1) ? W2 : W3);
  int l15 = lane & 15, lg = lane >> 4;
  bf16x8 fh, fl;
  #pragma unroll
  for (int e = 0; e < 8; ++e) {
    int k = kc * 32 + lg * 8 + e;
    float w = W[k * 64 + t * 16 + l15];
    __bf16 hi = (__bf16)w;
    fh[e] = hi;
    fl[e] = (__bf16)(w - (float)hi);
  }
  wbuf[i] = fh;
  wbuf[24 * 64 + i] = fl;
}

__device__ __forceinline__ void split8(const f32x4& v0, const f32x4& v1,
                                       bf16x8& hi, bf16x8& lo) {
  #pragma unroll
  for (int e = 0; e < 4; ++e) {
    __bf16 h0 = (__bf16)v0[e];
    __bf16 h1 = (__bf16)v1[e];
    hi[e] = h0;     lo[e] = (__bf16)(v0[e] - (float)h0);
    hi[4 + e] = h1; lo[4 + e] = (__bf16)(v1[e] - (float)h1);
  }
}

#define MFMA(A, B, C) __builtin_amdgcn_mfma_f32_16x16x32_bf16((A), (B), (C), 0, 0, 0)

#define DOT(L, T, BIASV, ACC)                                        \
  {                                                                  \
    bf16x8 bh0 = wbuf[(((L) * 2 + 0) * 4 + (T)) * 64 + lane];        \
    bf16x8 bh1 = wbuf[(((L) * 2 + 1) * 4 + (T)) * 64 + lane];        \
    bf16x8 bl0 = wbuf[1536 + (((L) * 2 + 0) * 4 + (T)) * 64 + lane]; \
    bf16x8 bl1 = wbuf[1536 + (((L) * 2 + 1) * 4 + (T)) * 64 + lane]; \
    f32x4 a_ = {(BIASV), (BIASV), (BIASV), (BIASV)};                 \
    a_ = MFMA(A0h, bh0, a_);                                         \
    a_ = MFMA(A1h, bh1, a_);                                         \
    a_ = MFMA(A0l, bh0, a_);                                         \
    a_ = MFMA(A1l, bh1, a_);                                         \
    a_ = MFMA(A0h, bl0, a_);                                         \
    a_ = MFMA(A1h, bl1, a_);                                         \
    ACC = a_;                                                        \
  }

#define DOLAYER(L)                   \
  DOT(L, 0, bias##L[0], acc0)        \
  DOT(L, 1, bias##L[1], acc1)        \
  DOT(L, 2, bias##L[2], acc2)        \
  DOT(L, 3, bias##L[3], acc3)

#define STORE_T(T, A)                                         \
  sc[(4 * lg + 0) * 68 + (T) * 16 + l15] = fmaxf(A[0], 0.f);  \
  sc[(4 * lg + 1) * 68 + (T) * 16 + l15] = fmaxf(A[1], 0.f);  \
  sc[(4 * lg + 2) * 68 + (T) * 16 + l15] = fmaxf(A[2], 0.f);  \
  sc[(4 * lg + 3) * 68 + (T) * 16 + l15] = fmaxf(A[3], 0.f);

#define TRANSITION                                            \
  {                                                           \
    STORE_T(0, acc0)                                          \
    STORE_T(1, acc1)                                          \
    STORE_T(2, acc2)                                          \
    STORE_T(3, acc3)                                          \
    const float* rp = sc + l15 * 68 + lg * 8;                 \
    f32x4 r0 = *(const f32x4*)(rp);                           \
    f32x4 r1 = *(const f32x4*)(rp + 4);                       \
    f32x4 r2 = *(const f32x4*)(rp + 32);                      \
    f32x4 r3 = *(const f32x4*)(rp + 36);                      \
    split8(r0, r1, A0h, A0l);                                 \
    split8(r2, r3, A1h, A1l);                                 \
  }

// epilogue col-tile: relu, bf16 store of RAW mlp output, BN partials -> LDS
#define EPI_T(T, A)                                                         \
  {                                                                         \
    float v0 = fmaxf(A[0], 0.f), v1 = fmaxf(A[1], 0.f);                     \
    float v2 = fmaxf(A[2], 0.f), v3 = fmaxf(A[3], 0.f);                     \
    if (active) {                                                           \
      xbout[(size_t)(rows0 + 4 * lg + 0) * DDIM + (T) * 16 + l15] = (__bf16)v0; \
      xbout[(size_t)(rows0 + 4 * lg + 1) * DDIM + (T) * 16 + l15] = (__bf16)v1; \
      xbout[(size_t)(rows0 + 4 * lg + 2) * DDIM + (T) * 16 + l15] = (__bf16)v2; \
      xbout[(size_t)(rows0 + 4 * lg + 3) * DDIM + (T) * 16 + l15] = (__bf16)v3; \
    }                                                                       \
    float vs = (v0 + v1) + (v2 + v3);                                       \
    float vq = ((v0 * v0 + v1 * v1) + (v2 * v2 + v3 * v3));                 \
    vs += __shfl_xor(vs, 16); vs += __shfl_xor(vs, 32);                     \
    vq += __shfl_xor(vq, 16); vq += __shfl_xor(vq, 32);                     \
    if (lane < 16) {                                                        \
      bnred[0][wave][(T) * 16 + l15] = vs;                                  \
      bnred[1][wave][(T) * 16 + l15] = vq;                                  \
    }                                                                       \
  }

// FUSED aggregate + MFMA MLP. Input xbin is the RAW (pre-BN) bf16 feature
// table of the previous iteration; the BN affine h = gm*x + bt is folded in
// analytically: total = gm*((1+eps)*x_v + sum_u x_u) + (1+eps+deg)*bt.
__global__ __launch_bounds__(512) void agg_mlp_kernel(
    const __bf16* __restrict__ xbin, const int* __restrict__ offs,
    const int* __restrict__ csr, const float* __restrict__ epsp,
    const float* __restrict__ gmbt, __bf16* __restrict__ xbout,
    const bf16x8* __restrict__ wbuf,
    const float* __restrict__ b1, const float* __restrict__ b2,
    const float* __restrict__ b3, float* __restrict__ partial) {
  __shared__ float xt[8 * 16 * 68];    // 34.8 KB: per-wave agg-out + scratch
  __shared__ float bnred[2][8][64];
  const int tid = threadIdx.x;
  const int lane = tid & 63, wave = tid >> 6;
  const int l15 = lane & 15, lg = lane >> 4;
  const int rows0 = blockIdx.x * 128 + wave * 16;
  const bool active = rows0 < N_NODES; // all-or-nothing per wave (50000 % 16 == 0)
  float* xw = xt + wave * (16 * 68);

  // ---- aggregate phase (with folded input affine)
  {
    const int fl = lane & 7, eg = lane >> 3;
    const uint4* __restrict__ hrow4 = (const uint4*)xbin;
    const float ep = 1.0f + epsp[0];
    f32x4 gA = *(const f32x4*)(gmbt + fl * 8);
    f32x4 gB = *(const f32x4*)(gmbt + fl * 8 + 4);
    f32x4 tA = *(const f32x4*)(gmbt + 64 + fl * 8);
    f32x4 tB = *(const f32x4*)(gmbt + 64 + fl * 8 + 4);
    #pragma unroll
    for (int pass = 0; pass < 2; ++pass) {
      const int node = rows0 + pass * 8 + eg;
      int beg = 0, end = 0;
      if (active) { beg = offs[node]; end = offs[node + 1]; }
      const int deg = end - beg;
      int maxdeg = deg;
      maxdeg = max(maxdeg, __shfl_xor(maxdeg, 8));
      maxdeg = max(maxdeg, __shfl_xor(maxdeg, 16));
      maxdeg = max(maxdeg, __shfl_xor(maxdeg, 32));

      float a0 = 0.f, a1 = 0.f, a2 = 0.f, a3 = 0.f,
            a4 = 0.f, a5 = 0.f, a6 = 0.f, a7 = 0.f;
      if (active) {
        uint4 w = hrow4[(size_t)node * 8 + fl];
        a0 = ep * blo16(w.x); a1 = ep * bhi16(w.x);
        a2 = ep * blo16(w.y); a3 = ep * bhi16(w.y);
        a4 = ep * blo16(w.z); a5 = ep * bhi16(w.z);
        a6 = ep * blo16(w.w); a7 = ep * bhi16(w.w);
      }
      #pragma unroll 4
      for (int it = 0; it < maxdeg; ++it) {
        bool act = it < deg;
        int ci = beg + it;
        ci = (ci < N_EDGES) ? ci : 0;
        int u = csr[ci];
        uint4 w = hrow4[(size_t)u * 8 + fl];
        unsigned m = act ? 0xffffffffu : 0u;
        w.x &= m; w.y &= m; w.z &= m; w.w &= m;
        a0 += blo16(w.x); a1 += bhi16(w.x);
        a2 += blo16(w.y); a3 += bhi16(w.y);
        a4 += blo16(w.z); a5 += bhi16(w.z);
        a6 += blo16(w.w); a7 += bhi16(w.w);
      }
      const float fdeg = ep + (float)deg;   // bt multiplier
      a0 = fmaf(gA[0], a0, fdeg * tA[0]); a1 = fmaf(gA[1], a1, fdeg * tA[1]);
      a2 = fmaf(gA[2], a2, fdeg * tA[2]); a3 = fmaf(gA[3], a3, fdeg * tA[3]);
      a4 = fmaf(gB[0], a4, fdeg * tB[0]); a5 = fmaf(gB[1], a5, fdeg * tB[1]);
      a6 = fmaf(gB[2], a6, fdeg * tB[2]); a7 = fmaf(gB[3], a7, fdeg * tB[3]);
      float* xp = xw + (pass * 8 + eg) * 68 + fl * 8;
      float4 o0 = {a0, a1, a2, a3};
      float4 o1 = {a4, a5, a6, a7};
      *(float4*)xp = o0;
      *(float4*)(xp + 4) = o1;
    }
  }
  // wave-private tile: no __syncthreads needed before MLP.

  f32x4 acc0 = {0.f, 0.f, 0.f, 0.f}, acc1 = acc0, acc2 = acc0, acc3 = acc0;
  if (active) {
    float bias0[4], bias1[4], bias2[4];
    #pragma unroll
    for (int t = 0; t < 4; ++t) {
      bias0[t] = b1[t * 16 + l15];
      bias1[t] = b2[t * 16 + l15];
      bias2[t] = b3[t * 16 + l15];
    }
    float* sc = xw;                    // reuse agg tile as TRANSITION scratch
    bf16x8 A0h, A0l, A1h, A1l;
    {
      const float* rp = xw + l15 * 68 + lg * 8;
      f32x4 r0 = *(const f32x4*)(rp);
      f32x4 r1 = *(const f32x4*)(rp + 4);
      f32x4 r2 = *(const f32x4*)(rp + 32);
      f32x4 r3 = *(const f32x4*)(rp + 36);
      split8(r0, r1, A0h, A0l);
      split8(r2, r3, A1h, A1l);
    }
    DOLAYER(0)
    TRANSITION
    DOLAYER(1)
    TRANSITION
    DOLAYER(2)
  }

  EPI_T(0, acc0)
  EPI_T(1, acc1)
  EPI_T(2, acc2)
  EPI_T(3, acc3)

  __syncthreads();
  if (tid < 128) {                     // transposed: partial[col][block]
    int s = tid >> 6, c = tid & 63;
    float t = 0.f;
    #pragma unroll
    for (int w = 0; w < 8; ++w) t += bnred[s][w][c];
    partial[(size_t)tid * PPITCH + blockIdx.x] = t;
  }
}

// wave per feature d: reduce sum & sq partials, emit gm[d], bt[d]
__global__ void bn_stats_kernel(const float* __restrict__ partial,
                                const float* __restrict__ gamma,
                                const float* __restrict__ beta,
                                float* __restrict__ gmbt) {
  int d = blockIdx.x * 4 + (threadIdx.x >> 6);     // 16 blocks x 4 waves = 64 feats
  int lane = threadIdx.x & 63;
  const float* rs = partial + (size_t)d * PPITCH;
  const float* rq = partial + (size_t)(64 + d) * PPITCH;
  float s = 0.f, q = 0.f;
  for (int i = lane; i < NBLK; i += 64) { s += rs[i]; q += rq[i]; }
  #pragma unroll
  for (int off = 32; off > 0; off >>= 1) {
    s += __shfl_down(s, off);
    q += __shfl_down(q, off);
  }
  if (lane == 0) {
    const float invN = 1.0f / N_NODES;
    float mean = s * invN;
    float var = q * invN - mean * mean;
    float gm = gamma[d] / sqrtf(var + 1e-5f);
    gmbt[d] = gm;
    gmbt[64 + d] = beta[d] - mean * gm;
  }
}

// graph pooling from RAW bf16 features: pooled[g] = gm*sum_g(xb) + |g|*bt
__global__ void pool_kernel(const unsigned* __restrict__ xbu, const int* __restrict__ goff,
                            const float* __restrict__ gmbt, float* __restrict__ pooled,
                            int iter) {
  const int g = blockIdx.x;
  const int tid = threadIdx.x;         // 256
  const int c = tid & 31;              // dword column (features 2c, 2c+1)
  const int slot = tid >> 5;           // 0..7
  const int rbeg = goff[g], rend = goff[g + 1];
  float a0 = 0.f, a1 = 0.f;
  for (int r = rbeg + slot; r < rend; r += 8) {
    unsigned w = xbu[(size_t)r * 32 + c];
    a0 += blo16(w);
    a1 += bhi16(w);
  }
  __shared__ float red[8][64];
  red[slot][2 * c] = a0;
  red[slot][2 * c + 1] = a1;
  __syncthreads();
  if (tid < 64) {
    float s = 0.f;
    #pragma unroll
    for (int k = 0; k < 8; ++k) s += red[k][tid];
    float cnt = (float)(rend - rbeg);
    pooled[(size_t)g * (ITERS * DDIM) + iter * DDIM + tid] =
        fmaf(gmbt[tid], s, cnt * gmbt[64 + tid]);
  }
}

__global__ void classifier_kernel(const float* __restrict__ pooled, const float* __restrict__ Wc,
                                  const float* __restrict__ bc, float* __restrict__ out) {
  int g = blockIdx.x;
  int c = threadIdx.x;
  if (c >= N_CLASSES) return;
  float acc = bc[c];
  #pragma unroll 4
  for (int k = 0; k < ITERS * DDIM; ++k)
    acc = fmaf(pooled[(size_t)g * (ITERS * DDIM) + k], Wc[k * N_CLASSES + c], acc);
  out[(size_t)g * N_CLASSES + c] = acc;
}

extern "C" void kernel_launch(void* const* d_in, const int* in_sizes, int n_in,
                              void* d_out, int out_size, void* d_ws, size_t ws_size,
                              hipStream_t stream) {
  const int*   pkt   = (const int*)d_in[0];
  const int*   src   = (const int*)d_in[1];
  const int*   dst   = (const int*)d_in[2];
  const int*   gids  = (const int*)d_in[3];
  const float* emb   = (const float*)d_in[4];
  const float* eps   = (const float*)d_in[5];
  const float* W1    = (const float*)d_in[6];
  const float* b1    = (const float*)d_in[7];
  const float* W2    = (const float*)d_in[8];
  const float* b2    = (const float*)d_in[9];
  const float* W3    = (const float*)d_in[10];
  const float* b3    = (const float*)d_in[11];
  const float* gamma = (const float*)d_in[12];
  const float* beta  = (const float*)d_in[13];
  const float* Wc    = (const float*)d_in[14];
  const float* bc    = (const float*)d_in[15];
  float* out = (float*)d_out;

  char* p = (char*)d_ws;
  auto alloc = [&](size_t bytes) {
    char* r = p;
    p += (bytes + 255) & ~(size_t)255;
    return r;
  };
  __bf16*   hb      = (__bf16*)alloc((size_t)N_NODES * DDIM * 2);
  __bf16*   xb0     = (__bf16*)alloc((size_t)N_NODES * DDIM * 2);
  __bf16*   xb1     = (__bf16*)alloc((size_t)N_NODES * DDIM * 2);
  unsigned* ebuf    = (unsigned*)alloc((size_t)N_EDGES * 4);
  int*      csr     = (int*)alloc((size_t)N_EDGES * 4);
  int*      offs    = (int*)alloc((size_t)(N_NODES + 1) * 4);
  int*      boffs   = (int*)alloc((size_t)(NB + 1) * 4);
  int*      bcursor = (int*)alloc((size_t)NB * 4);
  int*      goff    = (int*)alloc((size_t)(N_GRAPHS + 1) * 4);
  float*    pooled  = (float*)alloc((size_t)N_GRAPHS * ITERS * DDIM * 4);
  float*    gmbt    = (float*)alloc(128 * 4);
  float*    gmbt_id = (float*)alloc(128 * 4);
  bf16x8*   wbuf    = (bf16x8*)alloc((size_t)48 * 64 * 16);   // hi + lo fragments
  float*    partial = (float*)alloc((size_t)128 * PPITCH * 4);
  // contiguous zero region: bhist | gcnt  (zeroed by embed_kernel block 0)
  int*   zreg  = (int*)alloc((size_t)NZERO * 4);
  int*   bhist = zreg;
  int*   gcnt  = bhist + NB;

  embed_kernel<<<(N_NODES * 16 + 255) / 256, 256, 0, stream>>>(
      pkt, (const float4*)emb, (bf16x4*)hb, zreg, gmbt_id);
  bucket_hist_kernel<<<512, 256, 0, stream>>>(dst, bhist);
  hist_kernel<<<(N_NODES + 255) / 256, 256, 0, stream>>>(gids, gcnt, N_NODES);
  scans_kernel<<<2, 1024, 0, stream>>>(bhist, boffs, bcursor, gcnt, goff);
  partition_kernel<<<NPB, 1024, 0, stream>>>(src, dst, bcursor, ebuf);
  local_scatter_kernel<<<NB, 256, 0, stream>>>(ebuf, boffs, offs, csr);
  pack_weights_kernel<<<6, 256, 0, stream>>>(W1, W2, W3, wbuf);

  const __bf16* xin[ITERS]  = {hb, xb0, xb1};
  __bf16*       xout[ITERS] = {xb0, xb1, xb0};
  for (int it = 0; it < ITERS; ++it) {
    const float* aff = (it == 0) ? gmbt_id : gmbt;
    agg_mlp_kernel<<<NBLK, 512, 0, stream>>>(xin[it], offs, csr, eps, aff,
                                             xout[it], wbuf, b1, b2, b3, partial);
    bn_stats_kernel<<<16, 256, 0, stream>>>(partial, gamma, beta, gmbt);
    pool_kernel<<<N_GRAPHS, 256, 0, stream>>>((const unsigned*)xout[it], goff,
                                              gmbt, pooled, it);
  }
  classifier_kernel<<<N_GRAPHS, 64, 0, stream>>>(pooled, Wc, bc, out);
}